// Round 11
// baseline (137.055 us; speedup 1.0000x reference)
//
#include <hip/hip_runtime.h>

#define DEV __device__ __forceinline__

typedef __attribute__((ext_vector_type(8))) short bf16x8;
typedef __attribute__((ext_vector_type(4))) float f32x4;

static constexpr int NTH = 512;
static constexpr int TBE = 16;

// d_ws layout (bf16-element offsets) -- monolith/common section
static constexpr int W1P = 0;        // [128][32]  swz3 (K padded 16->32)
static constexpr int W2  = 4096;     // [128][128] swz7
static constexpr int WQ  = 20480;
static constexpr int WK  = 36864;
static constexpr int WVW = 53248;
static constexpr int OW  = 69632;
static constexpr int P1A = 86016;
static constexpr int P1B = 102400;
static constexpr int P2W = 118784;
static constexpr int WS_BF16_TOT = 135168;   // wsp (f32) follows, 2304 floats
static constexpr int NPRM = 18 * 128;
// split-path extras (bf16-element offsets)
static constexpr int WQr  = 139776;  // row-major bf16 copies
static constexpr int OWr  = 156160;
static constexpr int P1Ar = 172544;
static constexpr int P1Br = 188928;
static constexpr int P2r  = 205312;
static constexpr int WKt  = 221696;  // Wk TRANSPOSED [c'][j]: WKt[r][c] = Wk[c][r]
static constexpr int CURE = 238080;               // cur_emb [32768][128]
static constexpr int NBE  = 238080 + 4194304;     // nb_emb  [262144][128]
static constexpr size_t SPLIT_NEED = (size_t)(NBE + 33554432) * 2;  // ~76.0 MB
// param slots: 0 b1,1 g1,2 be1,3 b2,4 g2,5 be2,6 bq,7 bk,8 bv,9 out_b,
//              10 an_g,11 an_b,12 p1_b,13 p1_g,14 p1_be,15 p2_b,16 p2_g,17 p2_be

DEV unsigned short f2bf(float f) {
  unsigned u = __float_as_uint(f);
  return (unsigned short)((u + 0x7fffu + ((u >> 16) & 1u)) >> 16);
}
DEV float bf2f(unsigned short u) { return __uint_as_float(((unsigned)u) << 16); }

DEV void st_bf16(unsigned short* buf, int row, int col, float v) {
  buf[row * 128 + ((((col >> 3) ^ (row & 7)) << 3) | (col & 7))] = f2bf(v);
}
DEV float ld_bf16(const unsigned short* buf, int row, int col) {
  unsigned u = buf[row * 128 + ((((col >> 3) ^ (row & 7)) << 3) | (col & 7))];
  return __uint_as_float(u << 16);
}
DEV bf16x8 frag128(const unsigned short* buf, int row, int kk, int lg) {
  return *(const bf16x8*)(buf + row * 128 + (((kk * 4 + lg) ^ (row & 7)) << 3));
}
DEV bf16x8 frag32(const unsigned short* buf, int row, int lg) {
  return *(const bf16x8*)(buf + row * 32 + ((lg ^ (row & 3)) << 3));
}
DEV f32x4 mfma16(bf16x8 a, bf16x8 b, f32x4 c) {
  return __builtin_amdgcn_mfma_f32_16x16x32_bf16(a, b, c, 0, 0, 0);
}

// ---------------- prep: weights -> d_ws (swizzled + row-major + params) ----------------
__global__ void prep(const float* __restrict__ enc_w1, const float* __restrict__ enc_w2,
                     const float* __restrict__ in_pw, const float* __restrict__ out_w,
                     const float* __restrict__ p1_w, const float* __restrict__ p2_w,
                     const float* __restrict__ enc_b1, const float* __restrict__ enc_g1,
                     const float* __restrict__ enc_be1, const float* __restrict__ enc_b2,
                     const float* __restrict__ enc_g2, const float* __restrict__ enc_be2,
                     const float* __restrict__ in_pb, const float* __restrict__ out_b,
                     const float* __restrict__ an_g, const float* __restrict__ an_b,
                     const float* __restrict__ p1_b, const float* __restrict__ p1_g,
                     const float* __restrict__ p1_be, const float* __restrict__ p2_b,
                     const float* __restrict__ p2_g, const float* __restrict__ p2_be,
                     unsigned short* __restrict__ wsb, float* __restrict__ wsp, int rm) {
  int t = blockIdx.x * blockDim.x + threadIdx.x;
  int NT = gridDim.x * blockDim.x;
  for (int i = t; i < 8 * 16384; i += NT) {
    int mi = i >> 14, e = i & 16383, row = e >> 7, col = e & 127;
    float v; int dstb;
    switch (mi) {
      case 0: v = enc_w2[row * 128 + col];         dstb = W2;  break;
      case 1: v = in_pw[row * 128 + col];          dstb = WQ;  break;
      case 2: v = in_pw[(128 + row) * 128 + col];  dstb = WK;  break;
      case 3: v = in_pw[(256 + row) * 128 + col];  dstb = WVW; break;
      case 4: v = out_w[row * 128 + col];          dstb = OW;  break;
      case 5: v = p1_w[row * 256 + col];           dstb = P1A; break;
      case 6: v = p1_w[row * 256 + 128 + col];     dstb = P1B; break;
      default: v = p2_w[row * 128 + col];          dstb = P2W; break;
    }
    wsb[dstb + row * 128 + ((((col >> 3) ^ (row & 7)) << 3) | (col & 7))] = f2bf(v);
  }
  for (int i = t; i < 4096; i += NT) {
    int row = i >> 5, col = i & 31;
    float v = (col < 16) ? enc_w1[row * 16 + col] : 0.f;
    wsb[W1P + row * 32 + ((((col >> 3) ^ (row & 3)) << 3) | (col & 7))] = f2bf(v);
  }
  if (rm) {  // row-major bf16 copies for split-path direct global fragment reads
    for (int i = t; i < 6 * 16384; i += NT) {
      int mi = i >> 14, e = i & 16383, row = e >> 7, col = e & 127;
      float v; int dstb;
      switch (mi) {
        case 0: v = in_pw[row * 128 + col];         dstb = WQr;  break;
        case 1: v = out_w[row * 128 + col];         dstb = OWr;  break;
        case 2: v = p1_w[row * 256 + col];          dstb = P1Ar; break;
        case 3: v = p1_w[row * 256 + 128 + col];    dstb = P1Br; break;
        case 4: v = p2_w[row * 128 + col];          dstb = P2r;  break;
        default: v = in_pw[(128 + col) * 128 + row]; dstb = WKt; break;
      }
      wsb[dstb + e] = f2bf(v);
    }
  }
  for (int i = t; i < NPRM; i += NT) {
    int s = i >> 7, c = i & 127; float v;
    switch (s) {
      case 0: v = enc_b1[c]; break;  case 1: v = enc_g1[c]; break;
      case 2: v = enc_be1[c]; break; case 3: v = enc_b2[c]; break;
      case 4: v = enc_g2[c]; break;  case 5: v = enc_be2[c]; break;
      case 6: v = in_pb[c]; break;   case 7: v = in_pb[128 + c]; break;
      case 8: v = in_pb[256 + c]; break; case 9: v = out_b[c]; break;
      case 10: v = an_g[c]; break;   case 11: v = an_b[c]; break;
      case 12: v = p1_b[c]; break;   case 13: v = p1_g[c]; break;
      case 14: v = p1_be[c]; break;  case 15: v = p2_b[c]; break;
      case 16: v = p2_g[c]; break;   default: v = p2_be[c]; break;
    }
    wsp[i] = v;
  }
}

// ================= K1: encoder (coalesced I/O via LDS bounce) — proven r4 =================
__global__ __launch_bounds__(512, 4)
void k1_enc(const float* __restrict__ cur_x, const float* __restrict__ nb_x,
            const unsigned short* __restrict__ wsb, const float* __restrict__ wsp,
            unsigned short* __restrict__ wse) {
  __shared__ __align__(16) unsigned short s_w1[4096];
  __shared__ __align__(16) unsigned short s_w2[16384];
  __shared__ __align__(16) unsigned short s_h1[8][16 * 136];
  __shared__ float s_prm[6 * 128];

  const int tid = threadIdx.x;
  const int wv = tid >> 6, l = tid & 63, l15 = l & 15, lg = l >> 4;

  ((uint4*)s_w1)[tid] = ((const uint4*)(wsb + W1P))[tid];
#pragma unroll
  for (int i = 0; i < 4; ++i)
    ((uint4*)s_w2)[tid + i * 512] = ((const uint4*)(wsb + W2))[tid + i * 512];
  for (int i = tid; i < 768; i += 512) s_prm[i] = wsp[i];
  __syncthreads();

  unsigned short* h1 = &s_h1[wv][0];

  auto ln_t = [&](float (&acc)[8][4], int bs, int gs, int es, bool relu) {
#pragma unroll
    for (int ct = 0; ct < 8; ++ct) {
      float4 bb = *(const float4*)&s_prm[bs * 128 + ct * 16 + lg * 4];
      acc[ct][0] += bb.x; acc[ct][1] += bb.y; acc[ct][2] += bb.z; acc[ct][3] += bb.w;
    }
    float sm = 0.f, sq = 0.f;
#pragma unroll
    for (int ct = 0; ct < 8; ++ct)
#pragma unroll
      for (int r = 0; r < 4; ++r) { sm += acc[ct][r]; sq = fmaf(acc[ct][r], acc[ct][r], sq); }
    sm += __shfl_xor(sm, 16); sq += __shfl_xor(sq, 16);
    sm += __shfl_xor(sm, 32); sq += __shfl_xor(sq, 32);
    float mean = sm * 0.0078125f;
    float var = fmaf(sq, 0.0078125f, -mean * mean);
    float inv = rsqrtf(var + 1e-5f);
#pragma unroll
    for (int ct = 0; ct < 8; ++ct) {
      float4 gg = *(const float4*)&s_prm[gs * 128 + ct * 16 + lg * 4];
      float4 ee = *(const float4*)&s_prm[es * 128 + ct * 16 + lg * 4];
      float ga[4] = {gg.x, gg.y, gg.z, gg.w}, ea[4] = {ee.x, ee.y, ee.z, ee.w};
#pragma unroll
      for (int r = 0; r < 4; ++r) {
        float v = (acc[ct][r] - mean) * inv * ga[r] + ea[r];
        acc[ct][r] = relu ? fmaxf(v, 0.f) : v;
      }
    }
  };

#pragma unroll 1
  for (int t = blockIdx.x * 8 + wv; t < 18432; t += 9216) {
    asm volatile("s_waitcnt lgkmcnt(0)" ::: "memory");
    const bool isnb = t < 16384;
    const float* src = isnb ? nb_x + (size_t)t * 256
                            : cur_x + ((size_t)t - 16384) * 256;
    unsigned short* dst = wse + (isnb ? (size_t)NBE + (size_t)t * 2048
                                      : (size_t)CURE + ((size_t)t - 16384) * 2048);

    float4 fin = ((const float4*)src)[l];
    {
      uint2 u;
      u.x = (unsigned)f2bf(fin.x) | ((unsigned)f2bf(fin.y) << 16);
      u.y = (unsigned)f2bf(fin.z) | ((unsigned)f2bf(fin.w) << 16);
      *(uint2*)(h1 + (l >> 2) * 16 + (l & 3) * 4) = u;
    }
    bf16x8 bx = (bf16x8){0, 0, 0, 0, 0, 0, 0, 0};
    if (lg < 2) bx = *(const bf16x8*)(h1 + l15 * 16 + lg * 8);

    float acc[8][4];
#pragma unroll
    for (int ct = 0; ct < 8; ++ct) {
      f32x4 a = {0.f, 0.f, 0.f, 0.f};
      a = mfma16(frag32(s_w1, ct * 16 + l15, lg), bx, a);
      acc[ct][0] = a[0]; acc[ct][1] = a[1]; acc[ct][2] = a[2]; acc[ct][3] = a[3];
    }
    ln_t(acc, 0, 1, 2, true);
#pragma unroll
    for (int ct = 0; ct < 8; ++ct) {
      uint2 u;
      u.x = (unsigned)f2bf(acc[ct][0]) | ((unsigned)f2bf(acc[ct][1]) << 16);
      u.y = (unsigned)f2bf(acc[ct][2]) | ((unsigned)f2bf(acc[ct][3]) << 16);
      *(uint2*)(h1 + l15 * 136 + ct * 16 + lg * 4) = u;
    }

    bf16x8 bh[4];
#pragma unroll
    for (int kk = 0; kk < 4; ++kk)
      bh[kk] = *(const bf16x8*)(h1 + l15 * 136 + kk * 32 + lg * 8);
#pragma unroll
    for (int ct = 0; ct < 8; ++ct) {
      f32x4 a = {0.f, 0.f, 0.f, 0.f};
#pragma unroll
      for (int kk = 0; kk < 4; ++kk)
        a = mfma16(frag128(s_w2, ct * 16 + l15, kk, lg), bh[kk], a);
      acc[ct][0] = a[0]; acc[ct][1] = a[1]; acc[ct][2] = a[2]; acc[ct][3] = a[3];
    }
    ln_t(acc, 3, 4, 5, false);

#pragma unroll
    for (int ct = 0; ct < 8; ++ct) {
      uint2 u;
      u.x = (unsigned)f2bf(acc[ct][0]) | ((unsigned)f2bf(acc[ct][1]) << 16);
      u.y = (unsigned)f2bf(acc[ct][2]) | ((unsigned)f2bf(acc[ct][3]) << 16);
      int c = ct * 2 + (lg >> 1);
      *(uint2*)(h1 + l15 * 128 + ((c ^ l15) << 3) + (lg & 1) * 4) = u;
    }
#pragma unroll
    for (int i = 0; i < 4; ++i) {
      int R = i * 4 + lg;
      int j = l15;
      uint4 u = *(const uint4*)(h1 + R * 128 + ((j ^ R) << 3));
      ((uint4*)dst)[i * 64 + l] = u;
    }
  }
}

// ===== K2 v9: r4-skeleton + r6's VERIFIED per-head reassociation + nb-in-LDS =====
// r10 post-mortem: occupancy 2->3 blocks bought only 4% -> serial phase-chain bound.
// Shorten the chain: drop K/V GEMMs (128 of 168 MFMAs) via qk_h = Wk_h^T q_h (r6 math,
// passed absmax 0.031), with nb tile (exactly 32KB/block) LDS-resident from ONE
// coalesced HBM load; scores/pnb are cheap VALU over LDS. 56 MFMA/wave. No WK/WV
// staging. s_qk and s_pnb share one 16KB region (barrier-separated); s_f/s_agg alias
// dead s_nb; s_hh aliases dead s_q. 60.8 KB -> 2 blocks/CU.
__global__ __launch_bounds__(256, 2)
void k2_head(const int* __restrict__ nb_mask,
             const unsigned short* __restrict__ wsb, const float* __restrict__ wsp,
             float* __restrict__ out) {
  __shared__ __align__(16) unsigned char smem[62272];
  unsigned short* s_nb  = (unsigned short*)smem;               // [16e][8n][128c], dead after pnb reads
  float*          s_f   = (float*)smem;                        // alias (live OUT..)
  unsigned short* s_agg = (unsigned short*)(smem + 8448);      // alias (live after LN-an)
  unsigned short* s_qk  = (unsigned short*)(smem + 32768);     // [16e][4h][128c'], live qk->scores
  unsigned short* s_pnb = (unsigned short*)(smem + 32768);     // alias, live pnb->ctx
  unsigned short* s_q   = (unsigned short*)(smem + 49152);     // live Q->qk
  unsigned short* s_hh  = (unsigned short*)(smem + 49152);     // alias (live after LN-p1)
  unsigned short* s_cur = (unsigned short*)(smem + 53504);
  unsigned short* s_ctx = (unsigned short*)(smem + 57856);
  int*            s_mask = (int*)(smem + 62208);

  const int tid = threadIdx.x;
  const int wv = tid >> 6, l = tid & 63, l15 = l & 15, lg = l >> 4;
  const int ebase = blockIdx.x * TBE;

  // init: cur tile, nb tile (32KB, fully coalesced), masks
  {
    int row = tid >> 4, chunk = tid & 15;
    ((uint4*)s_cur)[row * 17 + chunk] = ((const uint4*)(wsb + CURE))[(size_t)ebase * 16 + tid];
  }
  {
    const uint4* src = (const uint4*)(wsb + NBE + (size_t)ebase * 1024);
#pragma unroll
    for (int i = 0; i < 8; ++i)
      ((uint4*)s_nb)[i * 256 + tid] = src[i * 256 + tid];
  }
  if (tid < 16) {
    int m = 0; const int* mp = nb_mask + (size_t)(ebase + tid) * 8;
#pragma unroll
    for (int n = 0; n < 8; ++n) m |= (mp[n] > 0) << n;
    s_mask[tid] = m;
  }
  __syncthreads();                                         // B1

  // ---- Q: A=cur rows (global), B=Wq rows (global) -> s_q bf16 (pre-scaled) ----
  {
    bf16x8 a[4];
#pragma unroll
    for (int kk = 0; kk < 4; ++kk)
      a[kk] = *(const bf16x8*)(wsb + CURE + ((size_t)(ebase + l15)) * 128 + kk * 32 + lg * 8);
#pragma unroll
    for (int u = 0; u < 2; ++u) {
      int nt = wv * 2 + u;
      f32x4 acc = {0.f, 0.f, 0.f, 0.f};
#pragma unroll
      for (int kk = 0; kk < 4; ++kk) {
        bf16x8 b = *(const bf16x8*)(wsb + WQr + (nt * 16 + l15) * 128 + kk * 32 + lg * 8);
        acc = mfma16(a[kk], b, acc);
      }
      int c = nt * 16 + l15;
      float bq = wsp[6 * 128 + c];
#pragma unroll
      for (int r = 0; r < 4; ++r)
        s_q[(lg * 4 + r) * 136 + c] = f2bf((acc[r] + bq) * 0.17677669529663687f);
    }
  }
  __builtin_amdgcn_sched_barrier(0);

  // ---- qk_h (h = wv): 8 tiles over ALL 128 c', K=32 (head-wv q chans).
  // In-wave dep: wave wv's q chans (32wv..) were written by wave wv in Q phase.
  {
    bf16x8 qb = *(const bf16x8*)(s_q + l15 * 136 + wv * 32 + lg * 8);
    __builtin_amdgcn_sched_barrier(0);
#pragma unroll
    for (int ct = 0; ct < 8; ++ct) {
      bf16x8 w = *(const bf16x8*)(wsb + WKt + (ct * 16 + l15) * 128 + wv * 32 + lg * 8);
      f32x4 a4 = {0.f, 0.f, 0.f, 0.f};
      a4 = mfma16(w, qb, a4);
      uint2 uu;
      uu.x = (unsigned)f2bf(a4[0]) | ((unsigned)f2bf(a4[1]) << 16);
      uu.y = (unsigned)f2bf(a4[2]) | ((unsigned)f2bf(a4[3]) << 16);
      *(uint2*)(s_qk + l15 * 512 + wv * 128 + ct * 16 + lg * 4) = uu;
    }
  }
  __syncthreads();                                         // B2

  // ---- scores: lane = (elem e = wv*4+lg, chans c0=l15*8); all 4 heads; in-lane softmax ----
  float p[4][8];
  {
    const int e = wv * 4 + lg;
    const int c0 = l15 * 8;
    float qf[4][8];
#pragma unroll
    for (int h = 0; h < 4; ++h) {
      bf16x8 q8 = *(const bf16x8*)(s_qk + e * 512 + h * 128 + c0);
#pragma unroll
      for (int i = 0; i < 8; ++i) qf[h][i] = bf2f((unsigned short)q8[i]);
    }
    float sp[4][8];
#pragma unroll
    for (int h = 0; h < 4; ++h)
#pragma unroll
      for (int n = 0; n < 8; ++n) sp[h][n] = 0.f;
#pragma unroll
    for (int n = 0; n < 8; ++n) {
      bf16x8 nb8 = *(const bf16x8*)(s_nb + (e * 8 + n) * 128 + c0);
#pragma unroll
      for (int i = 0; i < 8; ++i) {
        float v = bf2f((unsigned short)nb8[i]);
#pragma unroll
        for (int h = 0; h < 4; ++h) sp[h][n] = fmaf(qf[h][i], v, sp[h][n]);
      }
    }
#pragma unroll
    for (int h = 0; h < 4; ++h)
#pragma unroll
      for (int n = 0; n < 8; ++n) {
        sp[h][n] += __shfl_xor(sp[h][n], 1);
        sp[h][n] += __shfl_xor(sp[h][n], 2);
        sp[h][n] += __shfl_xor(sp[h][n], 4);
        sp[h][n] += __shfl_xor(sp[h][n], 8);
      }
    int m = s_mask[e];
    bool all = (m == 0);
#pragma unroll
    for (int h = 0; h < 4; ++h) {
      float mx = -1e30f;
#pragma unroll
      for (int n = 0; n < 8; ++n) {
        bool u = all || ((m >> n) & 1);
        mx = fmaxf(mx, u ? sp[h][n] : -1e30f);
      }
      float su = 0.f;
#pragma unroll
      for (int n = 0; n < 8; ++n) {
        bool u = all || ((m >> n) & 1);
        p[h][n] = u ? __expf(sp[h][n] - mx) : 0.f;
        su += p[h][n];
      }
      float inv = 1.f / su;
#pragma unroll
      for (int n = 0; n < 8; ++n) p[h][n] *= inv;
    }
  }
  __syncthreads();                                         // B3 (qk reads done; region becomes s_pnb)

  // ---- pnb: second LDS pass over nb; write [e][h][c0..c0+8) for all 4 heads ----
  {
    const int e = wv * 4 + lg;
    const int c0 = l15 * 8;
    float pn[4][8];
#pragma unroll
    for (int h = 0; h < 4; ++h)
#pragma unroll
      for (int i = 0; i < 8; ++i) pn[h][i] = 0.f;
#pragma unroll
    for (int n = 0; n < 8; ++n) {
      bf16x8 nb8 = *(const bf16x8*)(s_nb + (e * 8 + n) * 128 + c0);
#pragma unroll
      for (int i = 0; i < 8; ++i) {
        float v = bf2f((unsigned short)nb8[i]);
#pragma unroll
        for (int h = 0; h < 4; ++h) pn[h][i] = fmaf(p[h][n], v, pn[h][i]);
      }
    }
#pragma unroll
    for (int h = 0; h < 4; ++h) {
      uint4 u;
      u.x = (unsigned)f2bf(pn[h][0]) | ((unsigned)f2bf(pn[h][1]) << 16);
      u.y = (unsigned)f2bf(pn[h][2]) | ((unsigned)f2bf(pn[h][3]) << 16);
      u.z = (unsigned)f2bf(pn[h][4]) | ((unsigned)f2bf(pn[h][5]) << 16);
      u.w = (unsigned)f2bf(pn[h][6]) | ((unsigned)f2bf(pn[h][7]) << 16);
      *(uint4*)(s_pnb + e * 512 + h * 128 + c0) = u;
    }
  }
  __syncthreads();                                         // B4

  // ---- ctx (head wv): chans 32wv..32wv+32 for ALL elems = Wv @ pnb_wv (+bv) ----
  {
    bf16x8 b[4];
#pragma unroll
    for (int kk = 0; kk < 4; ++kk)
      b[kk] = *(const bf16x8*)(s_pnb + l15 * 512 + wv * 128 + kk * 32 + lg * 8);
#pragma unroll
    for (int u = 0; u < 2; ++u) {
      int ct = wv * 2 + u;
      f32x4 a4 = {0.f, 0.f, 0.f, 0.f};
#pragma unroll
      for (int kk = 0; kk < 4; ++kk)
        a4 = mfma16(frag128(wsb + WVW, ct * 16 + l15, kk, lg), b[kk], a4);
      float4 bb = *(const float4*)&wsp[8 * 128 + ct * 16 + lg * 4];
      uint2 uu;
      uu.x = (unsigned)f2bf(a4[0] + bb.x) | ((unsigned)f2bf(a4[1] + bb.y) << 16);
      uu.y = (unsigned)f2bf(a4[2] + bb.z) | ((unsigned)f2bf(a4[3] + bb.w) << 16);
      *(uint2*)(s_ctx + l15 * 136 + ct * 16 + lg * 4) = uu;
    }
  }
  __syncthreads();                                         // B5 (s_nb fully dead from here)

  // ---- OUT proj -> s_f (f32, aliases s_nb[0,8448)) ----
  {
    bf16x8 a[4];
#pragma unroll
    for (int kk = 0; kk < 4; ++kk)
      a[kk] = *(const bf16x8*)(s_ctx + l15 * 136 + kk * 32 + lg * 8);
#pragma unroll
    for (int u = 0; u < 2; ++u) {
      int nt = wv * 2 + u;
      f32x4 acc = {0.f, 0.f, 0.f, 0.f};
#pragma unroll
      for (int kk = 0; kk < 4; ++kk) {
        bf16x8 b = *(const bf16x8*)(wsb + OWr + (nt * 16 + l15) * 128 + kk * 32 + lg * 8);
        acc = mfma16(a[kk], b, acc);
      }
      int c = nt * 16 + l15;
      float bo = wsp[9 * 128 + c];
#pragma unroll
      for (int r = 0; r < 4; ++r) s_f[(lg * 4 + r) * 132 + c] = acc[r] + bo;
    }
  }
  __syncthreads();                                         // B6

  // ---- LN(an) + agg select -> s_agg (aliases s_nb[8448,12800)) ----
  {
    int eo = wv * 4 + (l >> 4);
    float4 x0 = *(const float4*)&s_f[eo * 132 + l15 * 8];
    float4 x1 = *(const float4*)&s_f[eo * 132 + l15 * 8 + 4];
    float xa[8] = {x0.x, x0.y, x0.z, x0.w, x1.x, x1.y, x1.z, x1.w};
    float sm = 0.f, sq = 0.f;
#pragma unroll
    for (int j = 0; j < 8; ++j) { sm += xa[j]; sq = fmaf(xa[j], xa[j], sq); }
#pragma unroll
    for (int off = 1; off <= 8; off <<= 1) { sm += __shfl_xor(sm, off); sq += __shfl_xor(sq, off); }
    float mean = sm * 0.0078125f;
    float var = fmaf(sq, 0.0078125f, -mean * mean);
    float inv = rsqrtf(var + 1e-5f);
    int m = s_mask[eo];
    unsigned short o8[8];
    const unsigned short* cu = s_cur + eo * 136 + l15 * 8;
#pragma unroll
    for (int j = 0; j < 8; ++j) {
      int c = l15 * 8 + j;
      float v = (xa[j] - mean) * inv * wsp[10 * 128 + c] + wsp[11 * 128 + c];
      o8[j] = m ? f2bf(v) : cu[j];
    }
    uint4 u;
    u.x = (unsigned)o8[0] | ((unsigned)o8[1] << 16);
    u.y = (unsigned)o8[2] | ((unsigned)o8[3] << 16);
    u.z = (unsigned)o8[4] | ((unsigned)o8[5] << 16);
    u.w = (unsigned)o8[6] | ((unsigned)o8[7] << 16);
    *(uint4*)(s_agg + eo * 136 + l15 * 8) = u;
  }
  __syncthreads();                                         // B7

  // ---- P1 = [cur|agg] @ p1^T -> s_f ----
  {
    bf16x8 ac[4], ag[4];
#pragma unroll
    for (int kk = 0; kk < 4; ++kk) {
      ac[kk] = *(const bf16x8*)(s_cur + l15 * 136 + kk * 32 + lg * 8);
      ag[kk] = *(const bf16x8*)(s_agg + l15 * 136 + kk * 32 + lg * 8);
    }
#pragma unroll
    for (int u = 0; u < 2; ++u) {
      int nt = wv * 2 + u;
      f32x4 acc = {0.f, 0.f, 0.f, 0.f};
#pragma unroll
      for (int kk = 0; kk < 4; ++kk) {
        bf16x8 b = *(const bf16x8*)(wsb + P1Ar + (nt * 16 + l15) * 128 + kk * 32 + lg * 8);
        acc = mfma16(ac[kk], b, acc);
      }
#pragma unroll
      for (int kk = 0; kk < 4; ++kk) {
        bf16x8 b = *(const bf16x8*)(wsb + P1Br + (nt * 16 + l15) * 128 + kk * 32 + lg * 8);
        acc = mfma16(ag[kk], b, acc);
      }
      int c = nt * 16 + l15;
      float bb = wsp[12 * 128 + c];
#pragma unroll
      for (int r = 0; r < 4; ++r) s_f[(lg * 4 + r) * 132 + c] = acc[r] + bb;
    }
  }
  __syncthreads();                                         // B8

  // ---- LN(p1)+ReLU -> s_hh (aliases dead s_q) ----
  {
    int eo = wv * 4 + (l >> 4);
    float4 x0 = *(const float4*)&s_f[eo * 132 + l15 * 8];
    float4 x1 = *(const float4*)&s_f[eo * 132 + l15 * 8 + 4];
    float xa[8] = {x0.x, x0.y, x0.z, x0.w, x1.x, x1.y, x1.z, x1.w};
    float sm = 0.f, sq = 0.f;
#pragma unroll
    for (int j = 0; j < 8; ++j) { sm += xa[j]; sq = fmaf(xa[j], xa[j], sq); }
#pragma unroll
    for (int off = 1; off <= 8; off <<= 1) { sm += __shfl_xor(sm, off); sq += __shfl_xor(sq, off); }
    float mean = sm * 0.0078125f;
    float var = fmaf(sq, 0.0078125f, -mean * mean);
    float inv = rsqrtf(var + 1e-5f);
    unsigned short o8[8];
#pragma unroll
    for (int j = 0; j < 8; ++j) {
      int c = l15 * 8 + j;
      float v = (xa[j] - mean) * inv * wsp[13 * 128 + c] + wsp[14 * 128 + c];
      o8[j] = f2bf(fmaxf(v, 0.f));
    }
    uint4 u;
    u.x = (unsigned)o8[0] | ((unsigned)o8[1] << 16);
    u.y = (unsigned)o8[2] | ((unsigned)o8[3] << 16);
    u.z = (unsigned)o8[4] | ((unsigned)o8[5] << 16);
    u.w = (unsigned)o8[6] | ((unsigned)o8[7] << 16);
    *(uint4*)(s_hh + eo * 136 + l15 * 8) = u;
  }
  __syncthreads();                                         // B9

  // ---- P2 -> s_f ----
  {
    bf16x8 a[4];
#pragma unroll
    for (int kk = 0; kk < 4; ++kk)
      a[kk] = *(const bf16x8*)(s_hh + l15 * 136 + kk * 32 + lg * 8);
#pragma unroll
    for (int u = 0; u < 2; ++u) {
      int nt = wv * 2 + u;
      f32x4 acc = {0.f, 0.f, 0.f, 0.f};
#pragma unroll
      for (int kk = 0; kk < 4; ++kk) {
        bf16x8 b = *(const bf16x8*)(wsb + P2r + (nt * 16 + l15) * 128 + kk * 32 + lg * 8);
        acc = mfma16(a[kk], b, acc);
      }
      int c = nt * 16 + l15;
      float bb = wsp[15 * 128 + c];
#pragma unroll
      for (int r = 0; r < 4; ++r) s_f[(lg * 4 + r) * 132 + c] = acc[r] + bb;
    }
  }
  __syncthreads();                                         // B10

  // ---- final LN -> out ----
  {
    int eo = wv * 4 + (l >> 4);
    float4 x0 = *(const float4*)&s_f[eo * 132 + l15 * 8];
    float4 x1 = *(const float4*)&s_f[eo * 132 + l15 * 8 + 4];
    float xa[8] = {x0.x, x0.y, x0.z, x0.w, x1.x, x1.y, x1.z, x1.w};
    float sm = 0.f, sq = 0.f;
#pragma unroll
    for (int j = 0; j < 8; ++j) { sm += xa[j]; sq = fmaf(xa[j], xa[j], sq); }
#pragma unroll
    for (int off = 1; off <= 8; off <<= 1) { sm += __shfl_xor(sm, off); sq += __shfl_xor(sq, off); }
    float mean = sm * 0.0078125f;
    float var = fmaf(sq, 0.0078125f, -mean * mean);
    float inv = rsqrtf(var + 1e-5f);
    float o[8];
#pragma unroll
    for (int j = 0; j < 8; ++j) {
      int c = l15 * 8 + j;
      o[j] = (xa[j] - mean) * inv * wsp[16 * 128 + c] + wsp[17 * 128 + c];
    }
    float* op = out + (size_t)(ebase + eo) * 128 + l15 * 8;
    *(float4*)op = make_float4(o[0], o[1], o[2], o[3]);
    *(float4*)(op + 4) = make_float4(o[4], o[5], o[6], o[7]);
  }
}

// ================= fallback monolith (round-2, proven) =================
__global__ __launch_bounds__(NTH, 1)
void gcn_mfma(const float* __restrict__ cur_x, const float* __restrict__ nb_x,
              const int* __restrict__ nb_mask,
              const unsigned short* __restrict__ wsb, const float* __restrict__ wsp,
              float* __restrict__ out) {
  __shared__ __align__(16) unsigned short s_stage[20480];
  __shared__ __align__(16) unsigned short s_X[144 * 32];
  __shared__ __align__(16) unsigned short s_H[144 * 128];
  __shared__ __align__(16) unsigned short s_Enb[128 * 128];
  __shared__ __align__(16) unsigned short s_Ecur[16 * 128];
  __shared__ __align__(16) float s_q[16 * 132];
  __shared__ __align__(16) float s_p[16 * 32];
  __shared__ __align__(16) unsigned short s_ctx[16 * 128];
  __shared__ __align__(16) unsigned short s_agg[16 * 128];
  __shared__ __align__(16) unsigned short s_hh[16 * 128];
  __shared__ float s_prm[NPRM];
  __shared__ int s_mask[16];

  const int tid = threadIdx.x;
  const int wv = tid >> 6, l = tid & 63, l15 = l & 15, lg = l >> 4;
  const int sub = l >> 5, l32 = l & 31;
  const int ebase = blockIdx.x * TBE;
  const int eo = wv * 2 + sub;

  auto stage = [&](int srcOff) {
    const uint4* s = (const uint4*)(wsb + srcOff);
    uint4* d = (uint4*)s_stage;
#pragma unroll
    for (int i = 0; i < 4; ++i) d[tid + i * NTH] = s[tid + i * NTH];
  };
  auto ln_epi = [&](float (&vals)[8][4], int bslot, int gslot, int beslot, bool relu) {
    float sm[4] = {0, 0, 0, 0}, sq[4] = {0, 0, 0, 0};
#pragma unroll
    for (int nt = 0; nt < 8; ++nt) {
      float b = s_prm[bslot * 128 + nt * 16 + l15];
#pragma unroll
      for (int r = 0; r < 4; ++r) {
        float v = vals[nt][r] + b; vals[nt][r] = v;
        sm[r] += v; sq[r] = fmaf(v, v, sq[r]);
      }
    }
#pragma unroll
    for (int off = 8; off >= 1; off >>= 1)
#pragma unroll
      for (int r = 0; r < 4; ++r) {
        sm[r] += __shfl_xor(sm[r], off);
        sq[r] += __shfl_xor(sq[r], off);
      }
    float mean[4], inv[4];
#pragma unroll
    for (int r = 0; r < 4; ++r) {
      mean[r] = sm[r] * 0.0078125f;
      float var = fmaf(sq[r], 0.0078125f, -mean[r] * mean[r]);
      inv[r] = rsqrtf(var + 1e-5f);
    }
#pragma unroll
    for (int nt = 0; nt < 8; ++nt) {
      int col = nt * 16 + l15;
      float g = s_prm[gslot * 128 + col], be = s_prm[beslot * 128 + col];
#pragma unroll
      for (int r = 0; r < 4; ++r) {
        float v = (vals[nt][r] - mean[r]) * inv[r] * g + be;
        vals[nt][r] = relu ? fmaxf(v, 0.f) : v;
      }
    }
  };

  {
    const uint4* s = (const uint4*)(wsb + W1P);
    ((uint4*)(s_stage + 16384))[tid] = s[tid];
  }
  for (int i = tid; i < NPRM; i += NTH) s_prm[i] = wsp[i];
  for (int i = tid; i < 4608; i += NTH) {
    int row = i >> 5, col = i & 31;
    int e = (row * 57) >> 9, kind = row - e * 9;
    float v = 0.f;
    if (col < 16) {
      int ge = ebase + e;
      v = (kind == 0) ? cur_x[(size_t)ge * 16 + col]
                      : nb_x[((size_t)ge * 8 + (kind - 1)) * 16 + col];
    }
    s_X[row * 32 + ((((col >> 3) ^ (row & 3)) << 3) | (col & 7))] = f2bf(v);
  }
  if (tid < 16) {
    int m = 0; const int* mp = nb_mask + (size_t)(ebase + tid) * 8;
#pragma unroll
    for (int n = 0; n < 8; ++n) m |= (mp[n] > 0) << n;
    s_mask[tid] = m;
  }
  __syncthreads();

  stage(W2);
  for (int mt = wv; mt < 9; mt += 8) {
    bf16x8 a = frag32(s_X, mt * 16 + l15, lg);
    float vals[8][4];
#pragma unroll
    for (int nt = 0; nt < 8; ++nt) {
      f32x4 acc = {0.f, 0.f, 0.f, 0.f};
      acc = mfma16(a, frag32(s_stage + 16384, nt * 16 + l15, lg), acc);
#pragma unroll
      for (int r = 0; r < 4; ++r) vals[nt][r] = acc[r];
    }
    ln_epi(vals, 0, 1, 2, true);
#pragma unroll
    for (int nt = 0; nt < 8; ++nt)
#pragma unroll
      for (int r = 0; r < 4; ++r)
        st_bf16(s_H, mt * 16 + lg * 4 + r, nt * 16 + l15, vals[nt][r]);
  }
  __syncthreads();

  for (int mt = wv; mt < 9; mt += 8) {
    bf16x8 a[4];
#pragma unroll
    for (int kk = 0; kk < 4; ++kk) a[kk] = frag128(s_H, mt * 16 + l15, kk, lg);
    float vals[8][4];
#pragma unroll
    for (int nt = 0; nt < 8; ++nt) {
      f32x4 acc = {0.f, 0.f, 0.f, 0.f};
#pragma unroll
      for (int kk = 0; kk < 4; ++kk)
        acc = mfma16(a[kk], frag128(s_stage, nt * 16 + l15, kk, lg), acc);
#pragma unroll
      for (int r = 0; r < 4; ++r) vals[nt][r] = acc[r];
    }
    ln_epi(vals, 3, 4, 5, false);
#pragma unroll
    for (int nt = 0; nt < 8; ++nt) {
      int col = nt * 16 + l15;
#pragma unroll
      for (int r = 0; r < 4; ++r) {
        int R = mt * 16 + lg * 4 + r;
        int e = (R * 57) >> 9, kind = R - e * 9;
        if (kind == 0) st_bf16(s_Ecur, e, col, vals[nt][r]);
        else           st_bf16(s_Enb, e * 8 + kind - 1, col, vals[nt][r]);
      }
    }
  }
  __syncthreads();
  stage(WQ);
  __syncthreads();

  {
    f32x4 acc = {0.f, 0.f, 0.f, 0.f};
#pragma unroll
    for (int kk = 0; kk < 4; ++kk)
      acc = mfma16(frag128(s_Ecur, l15, kk, lg), frag128(s_stage, wv * 16 + l15, kk, lg), acc);
    int col = wv * 16 + l15; float bq = s_prm[6 * 128 + col];
#pragma unroll
    for (int r = 0; r < 4; ++r) s_q[(lg * 4 + r) * 132 + col] = acc[r] + bq;
  }
  __syncthreads();
  stage(WK);
  __syncthreads();

  {
    bf16x8 b[4];
#pragma unroll
    for (int kk = 0; kk < 4; ++kk) b[kk] = frag128(s_stage, wv * 16 + l15, kk, lg);
    int col = wv * 16 + l15; float bk = s_prm[7 * 128 + col];
#pragma unroll
    for (int mt = 0; mt < 8; ++mt) {
      f32x4 acc = {0.f, 0.f, 0.f, 0.f};
#pragma unroll
      for (int kk = 0; kk < 4; ++kk)
        acc = mfma16(frag128(s_Enb, mt * 16 + l15, kk, lg), b[kk], acc);
#pragma unroll
      for (int r = 0; r < 4; ++r)
        st_bf16(s_H, mt * 16 + lg * 4 + r, col, acc[r] + bk);
    }
  }
  __syncthreads();

  stage(WVW);
  {
    int h = l32 >> 3, n = l32 & 7;
    int krow = eo * 8 + n;
    float dot = 0.f;
#pragma unroll
    for (int j = 0; j < 4; ++j) {
      bf16x8 kf = *(const bf16x8*)(s_H + krow * 128 + (((h * 4 + j) ^ (krow & 7)) << 3));
      const float* qp = s_q + eo * 132 + h * 32 + j * 8;
      float4 q0 = *(const float4*)qp, q1 = *(const float4*)(qp + 4);
      dot = fmaf(__uint_as_float(((unsigned)(unsigned short)kf[0]) << 16), q0.x, dot);
      dot = fmaf(__uint_as_float(((unsigned)(unsigned short)kf[1]) << 16), q0.y, dot);
      dot = fmaf(__uint_as_float(((unsigned)(unsigned short)kf[2]) << 16), q0.z, dot);
      dot = fmaf(__uint_as_float(((unsigned)(unsigned short)kf[3]) << 16), q0.w, dot);
      dot = fmaf(__uint_as_float(((unsigned)(unsigned short)kf[4]) << 16), q1.x, dot);
      dot = fmaf(__uint_as_float(((unsigned)(unsigned short)kf[5]) << 16), q1.y, dot);
      dot = fmaf(__uint_as_float(((unsigned)(unsigned short)kf[6]) << 16), q1.z, dot);
      dot = fmaf(__uint_as_float(((unsigned)(unsigned short)kf[7]) << 16), q1.w, dot);
    }
    float sc = dot * 0.17677669529663687f;
    int m = s_mask[eo];
    bool use = (m == 0) || ((m >> n) & 1);
    float scm = use ? sc : -1e30f;
    float mx = scm;
#pragma unroll
    for (int off = 4; off >= 1; off >>= 1) mx = fmaxf(mx, __shfl_xor(mx, off));
    float p = use ? __expf(sc - mx) : 0.f;
    float sum = p;
#pragma unroll
    for (int off = 4; off >= 1; off >>= 1) sum += __shfl_xor(sum, off);
    s_p[eo * 32 + h * 8 + n] = p / sum;
  }
  __syncthreads();

  {
    bf16x8 b[4];
#pragma unroll
    for (int kk = 0; kk < 4; ++kk) b[kk] = frag128(s_stage, wv * 16 + l15, kk, lg);
    int col = wv * 16 + l15; float bv = s_prm[8 * 128 + col];
#pragma unroll
    for (int mt = 0; mt < 8; ++mt) {
      f32x4 acc = {0.f, 0.f, 0.f, 0.f};
#pragma unroll
      for (int kk = 0; kk < 4; ++kk)
        acc = mfma16(frag128(s_Enb, mt * 16 + l15, kk, lg), b[kk], acc);
#pragma unroll
      for (int r = 0; r < 4; ++r)
        st_bf16(s_H, mt * 16 + lg * 4 + r, col, acc[r] + bv);
    }
  }
  __syncthreads();

  stage(OW);
  {
#pragma unroll
    for (int cc = 0; cc < 4; ++cc) {
      int col = l32 + 32 * cc;
      float c = 0.f;
#pragma unroll
      for (int n = 0; n < 8; ++n)
        c = fmaf(s_p[eo * 32 + cc * 8 + n], ld_bf16(s_H, eo * 8 + n, col), c);
      st_bf16(s_ctx, eo, col, c);
    }
  }
  __syncthreads();

  {
    f32x4 acc = {0.f, 0.f, 0.f, 0.f};
#pragma unroll
    for (int kk = 0; kk < 4; ++kk)
      acc = mfma16(frag128(s_ctx, l15, kk, lg), frag128(s_stage, wv * 16 + l15, kk, lg), acc);
    int col = wv * 16 + l15; float bo = s_prm[9 * 128 + col];
#pragma unroll
    for (int r = 0; r < 4; ++r) s_q[(lg * 4 + r) * 132 + col] = acc[r] + bo;
  }
  __syncthreads();

  stage(P1A);
  {
    float4 x = *(const float4*)&s_q[eo * 132 + l32 * 4];
    float s = x.x + x.y + x.z + x.w;
    float qq = fmaf(x.x, x.x, fmaf(x.y, x.y, fmaf(x.z, x.z, x.w * x.w)));
#pragma unroll
    for (int off = 16; off >= 1; off >>= 1) { s += __shfl_xor(s, off); qq += __shfl_xor(qq, off); }
    float mean = s * 0.0078125f;
    float var = fmaf(qq, 0.0078125f, -mean * mean);
    float inv = rsqrtf(var + 1e-5f);
    int m = s_mask[eo];
    float xa[4] = {x.x, x.y, x.z, x.w}, r4[4];
#pragma unroll
    for (int c = 0; c < 4; ++c) {
      int col = l32 * 4 + c;
      float v = (xa[c] - mean) * inv * s_prm[10 * 128 + col] + s_prm[11 * 128 + col];
      r4[c] = m ? v : ld_bf16(s_Ecur, eo, col);
    }
    uint2 uu;
    uu.x = (unsigned)f2bf(r4[0]) | ((unsigned)f2bf(r4[1]) << 16);
    uu.y = (unsigned)f2bf(r4[2]) | ((unsigned)f2bf(r4[3]) << 16);
    *(uint2*)(s_agg + eo * 128 + (((l32 >> 1) ^ (eo & 7)) << 3) + (l32 & 1) * 4) = uu;
  }
  __syncthreads();

  f32x4 accP = {0.f, 0.f, 0.f, 0.f};
#pragma unroll
  for (int kk = 0; kk < 4; ++kk)
    accP = mfma16(frag128(s_Ecur, l15, kk, lg), frag128(s_stage, wv * 16 + l15, kk, lg), accP);
  __syncthreads();
  stage(P1B);
  __syncthreads();
  {
#pragma unroll
    for (int kk = 0; kk < 4; ++kk)
      accP = mfma16(frag128(s_agg, l15, kk, lg), frag128(s_stage, wv * 16 + l15, kk, lg), accP);
    int col = wv * 16 + l15; float b = s_prm[12 * 128 + col];
#pragma unroll
    for (int r = 0; r < 4; ++r) s_q[(lg * 4 + r) * 132 + col] = accP[r] + b;
  }
  __syncthreads();

  stage(P2W);
  {
    float4 x = *(const float4*)&s_q[eo * 132 + l32 * 4];
    float s = x.x + x.y + x.z + x.w;
    float qq = fmaf(x.x, x.x, fmaf(x.y, x.y, fmaf(x.z, x.z, x.w * x.w)));
#pragma unroll
    for (int off = 16; off >= 1; off >>= 1) { s += __shfl_xor(s, off); qq += __shfl_xor(qq, off); }
    float mean = s * 0.0078125f;
    float var = fmaf(qq, 0.0078125f, -mean * mean);
    float inv = rsqrtf(var + 1e-5f);
    float xa[4] = {x.x, x.y, x.z, x.w}, r4[4];
#pragma unroll
    for (int c = 0; c < 4; ++c) {
      int col = l32 * 4 + c;
      r4[c] = fmaxf((xa[c] - mean) * inv * s_prm[13 * 128 + col] + s_prm[14 * 128 + col], 0.f);
    }
    uint2 uu;
    uu.x = (unsigned)f2bf(r4[0]) | ((unsigned)f2bf(r4[1]) << 16);
    uu.y = (unsigned)f2bf(r4[2]) | ((unsigned)f2bf(r4[3]) << 16);
    *(uint2*)(s_hh + eo * 128 + (((l32 >> 1) ^ (eo & 7)) << 3) + (l32 & 1) * 4) = uu;
  }
  __syncthreads();

  {
    f32x4 acc = {0.f, 0.f, 0.f, 0.f};
#pragma unroll
    for (int kk = 0; kk < 4; ++kk)
      acc = mfma16(frag128(s_hh, l15, kk, lg), frag128(s_stage, wv * 16 + l15, kk, lg), acc);
    int col = wv * 16 + l15; float b = s_prm[15 * 128 + col];
#pragma unroll
    for (int r = 0; r < 4; ++r) s_q[(lg * 4 + r) * 132 + col] = acc[r] + b;
  }
  __syncthreads();

  {
    float4 x = *(const float4*)&s_q[eo * 132 + l32 * 4];
    float s = x.x + x.y + x.z + x.w;
    float qq = fmaf(x.x, x.x, fmaf(x.y, x.y, fmaf(x.z, x.z, x.w * x.w)));
#pragma unroll
    for (int off = 16; off >= 1; off >>= 1) { s += __shfl_xor(s, off); qq += __shfl_xor(qq, off); }
    float mean = s * 0.0078125f;
    float var = fmaf(qq, 0.0078125f, -mean * mean);
    float inv = rsqrtf(var + 1e-5f);
    float xa[4] = {x.x, x.y, x.z, x.w};
    float4 o;
    o.x = (xa[0] - mean) * inv * s_prm[16 * 128 + l32 * 4 + 0] + s_prm[17 * 128 + l32 * 4 + 0];
    o.y = (xa[1] - mean) * inv * s_prm[16 * 128 + l32 * 4 + 1] + s_prm[17 * 128 + l32 * 4 + 1];
    o.z = (xa[2] - mean) * inv * s_prm[16 * 128 + l32 * 4 + 2] + s_prm[17 * 128 + l32 * 4 + 2];
    o.w = (xa[3] - mean) * inv * s_prm[16 * 128 + l32 * 4 + 3] + s_prm[17 * 128 + l32 * 4 + 3];
    *(float4*)&out[(size_t)(ebase + eo) * 128 + l32 * 4] = o;
  }
}

extern "C" void kernel_launch(void* const* d_in, const int* in_sizes, int n_in,
                              void* d_out, int out_size, void* d_ws, size_t ws_size,
                              hipStream_t stream) {
  const float* cur_x   = (const float*)d_in[0];
  const float* nb_x    = (const float*)d_in[1];
  const int*   nbm     = (const int*)d_in[2];
  const float* enc_w1  = (const float*)d_in[3];
  const float* enc_b1  = (const float*)d_in[4];
  const float* enc_g1  = (const float*)d_in[5];
  const float* enc_be1 = (const float*)d_in[6];
  const float* enc_w2  = (const float*)d_in[7];
  const float* enc_b2  = (const float*)d_in[8];
  const float* enc_g2  = (const float*)d_in[9];
  const float* enc_be2 = (const float*)d_in[10];
  const float* in_pw   = (const float*)d_in[11];
  const float* in_pb   = (const float*)d_in[12];
  const float* out_w   = (const float*)d_in[13];
  const float* out_b   = (const float*)d_in[14];
  const float* an_g    = (const float*)d_in[15];
  const float* an_b    = (const float*)d_in[16];
  const float* p1_w    = (const float*)d_in[17];
  const float* p1_b    = (const float*)d_in[18];
  const float* p1_g    = (const float*)d_in[19];
  const float* p1_be   = (const float*)d_in[20];
  const float* p2_w    = (const float*)d_in[21];
  const float* p2_b    = (const float*)d_in[22];
  const float* p2_g    = (const float*)d_in[23];
  const float* p2_be   = (const float*)d_in[24];
  float* out = (float*)d_out;

  unsigned short* wsb = (unsigned short*)d_ws;
  float* wsp = (float*)(wsb + WS_BF16_TOT);
  const int B = in_sizes[0] / 16;
  const bool split = (ws_size >= SPLIT_NEED) && (B == 32768);

  prep<<<128, 256, 0, stream>>>(enc_w1, enc_w2, in_pw, out_w, p1_w, p2_w,
                                enc_b1, enc_g1, enc_be1, enc_b2, enc_g2, enc_be2,
                                in_pb, out_b, an_g, an_b, p1_b, p1_g, p1_be,
                                p2_b, p2_g, p2_be, wsb, wsp, split ? 1 : 0);

  if (split) {
    k1_enc<<<1152, 512, 0, stream>>>(cur_x, nb_x, wsb, wsp, wsb);
    k2_head<<<B / TBE, 256, 0, stream>>>(nbm, wsb, wsp, out);
  } else {
    gcn_mfma<<<B / TBE, NTH, 0, stream>>>(cur_x, nb_x, nbm, wsb, wsp, out);
  }
}

// Round 13
// 134.477 us; speedup vs baseline: 1.0192x; 1.0192x over previous
//
#include <hip/hip_runtime.h>

#define DEV __device__ __forceinline__

typedef __attribute__((ext_vector_type(8))) short bf16x8;
typedef __attribute__((ext_vector_type(4))) float f32x4;

static constexpr int NTH = 512;
static constexpr int TBE = 16;

// d_ws layout (bf16-element offsets) -- monolith/common section
static constexpr int W1P = 0;        // [128][32]  swz3 (K padded 16->32)
static constexpr int W2  = 4096;     // [128][128] swz7
static constexpr int WQ  = 20480;
static constexpr int WK  = 36864;
static constexpr int WVW = 53248;
static constexpr int OW  = 69632;
static constexpr int P1A = 86016;
static constexpr int P1B = 102400;
static constexpr int P2W = 118784;
static constexpr int WS_BF16_TOT = 135168;   // wsp (f32) follows, 2304 floats
static constexpr int NPRM = 18 * 128;
// split-path extras (bf16-element offsets)
static constexpr int WQr  = 139776;  // row-major bf16 copies
static constexpr int OWr  = 156160;
static constexpr int P1Ar = 172544;
static constexpr int P1Br = 188928;
static constexpr int P2r  = 205312;
static constexpr int WKt  = 221696;  // Wk TRANSPOSED (kept for layout compat)
static constexpr int CURE = 238080;               // cur_emb [32768][128]
static constexpr int NBE  = 238080 + 4194304;     // nb_emb  [262144][128]
static constexpr size_t SPLIT_NEED = (size_t)(NBE + 33554432) * 2;  // ~76.0 MB
// param slots: 0 b1,1 g1,2 be1,3 b2,4 g2,5 be2,6 bq,7 bk,8 bv,9 out_b,
//              10 an_g,11 an_b,12 p1_b,13 p1_g,14 p1_be,15 p2_b,16 p2_g,17 p2_be

DEV unsigned short f2bf(float f) {
  unsigned u = __float_as_uint(f);
  return (unsigned short)((u + 0x7fffu + ((u >> 16) & 1u)) >> 16);
}
DEV float bf2f(unsigned short u) { return __uint_as_float(((unsigned)u) << 16); }

DEV void st_bf16(unsigned short* buf, int row, int col, float v) {
  buf[row * 128 + ((((col >> 3) ^ (row & 7)) << 3) | (col & 7))] = f2bf(v);
}
DEV float ld_bf16(const unsigned short* buf, int row, int col) {
  unsigned u = buf[row * 128 + ((((col >> 3) ^ (row & 7)) << 3) | (col & 7))];
  return __uint_as_float(u << 16);
}
DEV bf16x8 frag128(const unsigned short* buf, int row, int kk, int lg) {
  return *(const bf16x8*)(buf + row * 128 + (((kk * 4 + lg) ^ (row & 7)) << 3));
}
DEV bf16x8 frag32(const unsigned short* buf, int row, int lg) {
  return *(const bf16x8*)(buf + row * 32 + ((lg ^ (row & 3)) << 3));
}
DEV f32x4 mfma16(bf16x8 a, bf16x8 b, f32x4 c) {
  return __builtin_amdgcn_mfma_f32_16x16x32_bf16(a, b, c, 0, 0, 0);
}

// ---------------- prep: weights -> d_ws (swizzled + row-major + params) ----------------
__global__ void prep(const float* __restrict__ enc_w1, const float* __restrict__ enc_w2,
                     const float* __restrict__ in_pw, const float* __restrict__ out_w,
                     const float* __restrict__ p1_w, const float* __restrict__ p2_w,
                     const float* __restrict__ enc_b1, const float* __restrict__ enc_g1,
                     const float* __restrict__ enc_be1, const float* __restrict__ enc_b2,
                     const float* __restrict__ enc_g2, const float* __restrict__ enc_be2,
                     const float* __restrict__ in_pb, const float* __restrict__ out_b,
                     const float* __restrict__ an_g, const float* __restrict__ an_b,
                     const float* __restrict__ p1_b, const float* __restrict__ p1_g,
                     const float* __restrict__ p1_be, const float* __restrict__ p2_b,
                     const float* __restrict__ p2_g, const float* __restrict__ p2_be,
                     unsigned short* __restrict__ wsb, float* __restrict__ wsp, int rm) {
  int t = blockIdx.x * blockDim.x + threadIdx.x;
  int NT = gridDim.x * blockDim.x;
  for (int i = t; i < 8 * 16384; i += NT) {
    int mi = i >> 14, e = i & 16383, row = e >> 7, col = e & 127;
    float v; int dstb;
    switch (mi) {
      case 0: v = enc_w2[row * 128 + col];         dstb = W2;  break;
      case 1: v = in_pw[row * 128 + col];          dstb = WQ;  break;
      case 2: v = in_pw[(128 + row) * 128 + col];  dstb = WK;  break;
      case 3: v = in_pw[(256 + row) * 128 + col];  dstb = WVW; break;
      case 4: v = out_w[row * 128 + col];          dstb = OW;  break;
      case 5: v = p1_w[row * 256 + col];           dstb = P1A; break;
      case 6: v = p1_w[row * 256 + 128 + col];     dstb = P1B; break;
      default: v = p2_w[row * 128 + col];          dstb = P2W; break;
    }
    wsb[dstb + row * 128 + ((((col >> 3) ^ (row & 7)) << 3) | (col & 7))] = f2bf(v);
  }
  for (int i = t; i < 4096; i += NT) {
    int row = i >> 5, col = i & 31;
    float v = (col < 16) ? enc_w1[row * 16 + col] : 0.f;
    wsb[W1P + row * 32 + ((((col >> 3) ^ (row & 3)) << 3) | (col & 7))] = f2bf(v);
  }
  if (rm) {  // row-major bf16 copies for split-path direct global fragment reads
    for (int i = t; i < 6 * 16384; i += NT) {
      int mi = i >> 14, e = i & 16383, row = e >> 7, col = e & 127;
      float v; int dstb;
      switch (mi) {
        case 0: v = in_pw[row * 128 + col];         dstb = WQr;  break;
        case 1: v = out_w[row * 128 + col];         dstb = OWr;  break;
        case 2: v = p1_w[row * 256 + col];          dstb = P1Ar; break;
        case 3: v = p1_w[row * 256 + 128 + col];    dstb = P1Br; break;
        case 4: v = p2_w[row * 128 + col];          dstb = P2r;  break;
        default: v = in_pw[(128 + col) * 128 + row]; dstb = WKt; break;
      }
      wsb[dstb + e] = f2bf(v);
    }
  }
  for (int i = t; i < NPRM; i += NT) {
    int s = i >> 7, c = i & 127; float v;
    switch (s) {
      case 0: v = enc_b1[c]; break;  case 1: v = enc_g1[c]; break;
      case 2: v = enc_be1[c]; break; case 3: v = enc_b2[c]; break;
      case 4: v = enc_g2[c]; break;  case 5: v = enc_be2[c]; break;
      case 6: v = in_pb[c]; break;   case 7: v = in_pb[128 + c]; break;
      case 8: v = in_pb[256 + c]; break; case 9: v = out_b[c]; break;
      case 10: v = an_g[c]; break;   case 11: v = an_b[c]; break;
      case 12: v = p1_b[c]; break;   case 13: v = p1_g[c]; break;
      case 14: v = p1_be[c]; break;  case 15: v = p2_b[c]; break;
      case 16: v = p2_g[c]; break;   default: v = p2_be[c]; break;
    }
    wsp[i] = v;
  }
}

// ================= K1: encoder (coalesced I/O via LDS bounce) — proven r4 =================
__global__ __launch_bounds__(512, 4)
void k1_enc(const float* __restrict__ cur_x, const float* __restrict__ nb_x,
            const unsigned short* __restrict__ wsb, const float* __restrict__ wsp,
            unsigned short* __restrict__ wse) {
  __shared__ __align__(16) unsigned short s_w1[4096];
  __shared__ __align__(16) unsigned short s_w2[16384];
  __shared__ __align__(16) unsigned short s_h1[8][16 * 136];
  __shared__ float s_prm[6 * 128];

  const int tid = threadIdx.x;
  const int wv = tid >> 6, l = tid & 63, l15 = l & 15, lg = l >> 4;

  ((uint4*)s_w1)[tid] = ((const uint4*)(wsb + W1P))[tid];
#pragma unroll
  for (int i = 0; i < 4; ++i)
    ((uint4*)s_w2)[tid + i * 512] = ((const uint4*)(wsb + W2))[tid + i * 512];
  for (int i = tid; i < 768; i += 512) s_prm[i] = wsp[i];
  __syncthreads();

  unsigned short* h1 = &s_h1[wv][0];

  auto ln_t = [&](float (&acc)[8][4], int bs, int gs, int es, bool relu) {
#pragma unroll
    for (int ct = 0; ct < 8; ++ct) {
      float4 bb = *(const float4*)&s_prm[bs * 128 + ct * 16 + lg * 4];
      acc[ct][0] += bb.x; acc[ct][1] += bb.y; acc[ct][2] += bb.z; acc[ct][3] += bb.w;
    }
    float sm = 0.f, sq = 0.f;
#pragma unroll
    for (int ct = 0; ct < 8; ++ct)
#pragma unroll
      for (int r = 0; r < 4; ++r) { sm += acc[ct][r]; sq = fmaf(acc[ct][r], acc[ct][r], sq); }
    sm += __shfl_xor(sm, 16); sq += __shfl_xor(sq, 16);
    sm += __shfl_xor(sm, 32); sq += __shfl_xor(sq, 32);
    float mean = sm * 0.0078125f;
    float var = fmaf(sq, 0.0078125f, -mean * mean);
    float inv = rsqrtf(var + 1e-5f);
#pragma unroll
    for (int ct = 0; ct < 8; ++ct) {
      float4 gg = *(const float4*)&s_prm[gs * 128 + ct * 16 + lg * 4];
      float4 ee = *(const float4*)&s_prm[es * 128 + ct * 16 + lg * 4];
      float ga[4] = {gg.x, gg.y, gg.z, gg.w}, ea[4] = {ee.x, ee.y, ee.z, ee.w};
#pragma unroll
      for (int r = 0; r < 4; ++r) {
        float v = (acc[ct][r] - mean) * inv * ga[r] + ea[r];
        acc[ct][r] = relu ? fmaxf(v, 0.f) : v;
      }
    }
  };

#pragma unroll 1
  for (int t = blockIdx.x * 8 + wv; t < 18432; t += 9216) {
    asm volatile("s_waitcnt lgkmcnt(0)" ::: "memory");
    const bool isnb = t < 16384;
    const float* src = isnb ? nb_x + (size_t)t * 256
                            : cur_x + ((size_t)t - 16384) * 256;
    unsigned short* dst = wse + (isnb ? (size_t)NBE + (size_t)t * 2048
                                      : (size_t)CURE + ((size_t)t - 16384) * 2048);

    float4 fin = ((const float4*)src)[l];
    {
      uint2 u;
      u.x = (unsigned)f2bf(fin.x) | ((unsigned)f2bf(fin.y) << 16);
      u.y = (unsigned)f2bf(fin.z) | ((unsigned)f2bf(fin.w) << 16);
      *(uint2*)(h1 + (l >> 2) * 16 + (l & 3) * 4) = u;
    }
    bf16x8 bx = (bf16x8){0, 0, 0, 0, 0, 0, 0, 0};
    if (lg < 2) bx = *(const bf16x8*)(h1 + l15 * 16 + lg * 8);

    float acc[8][4];
#pragma unroll
    for (int ct = 0; ct < 8; ++ct) {
      f32x4 a = {0.f, 0.f, 0.f, 0.f};
      a = mfma16(frag32(s_w1, ct * 16 + l15, lg), bx, a);
      acc[ct][0] = a[0]; acc[ct][1] = a[1]; acc[ct][2] = a[2]; acc[ct][3] = a[3];
    }
    ln_t(acc, 0, 1, 2, true);
#pragma unroll
    for (int ct = 0; ct < 8; ++ct) {
      uint2 u;
      u.x = (unsigned)f2bf(acc[ct][0]) | ((unsigned)f2bf(acc[ct][1]) << 16);
      u.y = (unsigned)f2bf(acc[ct][2]) | ((unsigned)f2bf(acc[ct][3]) << 16);
      *(uint2*)(h1 + l15 * 136 + ct * 16 + lg * 4) = u;
    }

    bf16x8 bh[4];
#pragma unroll
    for (int kk = 0; kk < 4; ++kk)
      bh[kk] = *(const bf16x8*)(h1 + l15 * 136 + kk * 32 + lg * 8);
#pragma unroll
    for (int ct = 0; ct < 8; ++ct) {
      f32x4 a = {0.f, 0.f, 0.f, 0.f};
#pragma unroll
      for (int kk = 0; kk < 4; ++kk)
        a = mfma16(frag128(s_w2, ct * 16 + l15, kk, lg), bh[kk], a);
      acc[ct][0] = a[0]; acc[ct][1] = a[1]; acc[ct][2] = a[2]; acc[ct][3] = a[3];
    }
    ln_t(acc, 3, 4, 5, false);

#pragma unroll
    for (int ct = 0; ct < 8; ++ct) {
      uint2 u;
      u.x = (unsigned)f2bf(acc[ct][0]) | ((unsigned)f2bf(acc[ct][1]) << 16);
      u.y = (unsigned)f2bf(acc[ct][2]) | ((unsigned)f2bf(acc[ct][3]) << 16);
      int c = ct * 2 + (lg >> 1);
      *(uint2*)(h1 + l15 * 128 + ((c ^ l15) << 3) + (lg & 1) * 4) = u;
    }
#pragma unroll
    for (int i = 0; i < 4; ++i) {
      int R = i * 4 + lg;
      int j = l15;
      uint4 u = *(const uint4*)(h1 + R * 128 + ((j ^ R) << 3));
      ((uint4*)dst)[i * 64 + l] = u;
    }
  }
}

// ===== K2 v7 (round-10 verified best: r4 structure + LDS alias diet, 96.5us) =====
// r11/r12 post-mortem: k2 ~96us is a barrier-phase latency chain floor — invariant to
// MFMA count (r11: -66% MFMA, +0%), occupancy (r10: +50% waves, +4%), and HBM (38MB,
// L3-resident). r12's TB2=32 amortization failed correctness; reverting to the
// verified best configuration.
__global__ __launch_bounds__(256, 2)
void k2_head(const int* __restrict__ nb_mask,
             const unsigned short* __restrict__ wsb, const float* __restrict__ wsp,
             float* __restrict__ out) {
  __shared__ __align__(16) unsigned char smem[47936];
  unsigned short* s_stage = (unsigned short*)smem;
  float*          s_f     = (float*)smem;                     // alias (live after B5)
  unsigned short* s_agg   = (unsigned short*)(smem + 8448);   // alias (live after B6)
  unsigned short* s_q     = (unsigned short*)(smem + 32768);
  unsigned short* s_hh    = (unsigned short*)(smem + 32768);  // alias of s_q (live after B8)
  unsigned short* s_cur   = (unsigned short*)(smem + 37120);
  unsigned short* s_ctx   = (unsigned short*)(smem + 41472);
  float*          s_p     = (float*)(smem + 45824);
  int*            s_mask  = (int*)(smem + 47872);

  const int tid = threadIdx.x;
  const int wv = tid >> 6, l = tid & 63, l15 = l & 15, lg = l >> 4;
  const int ebase = blockIdx.x * TBE;

  // init: cur_emb tile, masks
  {
    int row = tid >> 4, chunk = tid & 15;
    ((uint4*)s_cur)[row * 17 + chunk] = ((const uint4*)(wsb + CURE))[(size_t)ebase * 16 + tid];
  }
  if (tid < 16) {
    int m = 0; const int* mp = nb_mask + (size_t)(ebase + tid) * 8;
#pragma unroll
    for (int n = 0; n < 8; ++n) m |= (mp[n] > 0) << n;
    s_mask[tid] = m;
  }
  __syncthreads();                                         // B1

  // ---- Q: A=cur rows (global), B=Wq rows (global) -> s_q bf16 (pre-scaled) ----
  {
    bf16x8 a[4];
#pragma unroll
    for (int kk = 0; kk < 4; ++kk)
      a[kk] = *(const bf16x8*)(wsb + CURE + ((size_t)(ebase + l15)) * 128 + kk * 32 + lg * 8);
#pragma unroll
    for (int u = 0; u < 2; ++u) {
      int nt = wv * 2 + u;
      f32x4 acc = {0.f, 0.f, 0.f, 0.f};
#pragma unroll
      for (int kk = 0; kk < 4; ++kk) {
        bf16x8 b = *(const bf16x8*)(wsb + WQr + (nt * 16 + l15) * 128 + kk * 32 + lg * 8);
        acc = mfma16(a[kk], b, acc);
      }
      int c = nt * 16 + l15;
      float bq = wsp[6 * 128 + c];
#pragma unroll
      for (int r = 0; r < 4; ++r)
        s_q[(lg * 4 + r) * 136 + c] = f2bf((acc[r] + bq) * 0.17677669529663687f);
    }
  }
  // stage WK
#pragma unroll
  for (int i = 0; i < 8; ++i)
    ((uint4*)s_stage)[tid + i * 256] = ((const uint4*)(wsb + WK))[tid + i * 256];
  __syncthreads();                                         // B2

  // ---- scores: K-GEMM fused with q-consumption; softmax -> s_p ----
#pragma unroll 1
  for (int mi = 0; mi < 2; ++mi) {
    int mt = wv * 2 + mi;
    int el = mt * 2 + (lg >> 1);
    bf16x8 a[4];
#pragma unroll
    for (int kk = 0; kk < 4; ++kk)
      a[kk] = *(const bf16x8*)(wsb + NBE + ((size_t)ebase * 8 + mt * 16 + l15) * 128 + kk * 32 + lg * 8);
    float sacc[4][4];
#pragma unroll
    for (int h = 0; h < 4; ++h)
#pragma unroll
      for (int r = 0; r < 4; ++r) sacc[h][r] = 0.f;
#pragma unroll
    for (int nt = 0; nt < 8; ++nt) {
      f32x4 k4 = {0.f, 0.f, 0.f, 0.f};
#pragma unroll
      for (int kk = 0; kk < 4; ++kk)
        k4 = mfma16(a[kk], frag128(s_stage, nt * 16 + l15, kk, lg), k4);
      float qv = bf2f(s_q[el * 136 + nt * 16 + l15]);
      int h = nt >> 1;
#pragma unroll
      for (int r = 0; r < 4; ++r) sacc[h][r] = fmaf(k4[r], qv, sacc[h][r]);
    }
#pragma unroll
    for (int off = 1; off <= 8; off <<= 1)
#pragma unroll
      for (int h = 0; h < 4; ++h)
#pragma unroll
        for (int r = 0; r < 4; ++r) sacc[h][r] += __shfl_xor(sacc[h][r], off);
    int m = s_mask[el];
    int nbase = (lg & 1) * 4;
    float p[4][4];
#pragma unroll
    for (int h = 0; h < 4; ++h) {
      float mx = -1e30f;
#pragma unroll
      for (int r = 0; r < 4; ++r) {
        bool use = (m == 0) || ((m >> (nbase + r)) & 1);
        mx = fmaxf(mx, use ? sacc[h][r] : -1e30f);
      }
      mx = fmaxf(mx, __shfl_xor(mx, 16));
      float sum = 0.f;
#pragma unroll
      for (int r = 0; r < 4; ++r) {
        bool use = (m == 0) || ((m >> (nbase + r)) & 1);
        p[h][r] = use ? __expf(sacc[h][r] - mx) : 0.f;
        sum += p[h][r];
      }
      sum += __shfl_xor(sum, 16);
      float inv = 1.f / sum;
#pragma unroll
      for (int r = 0; r < 4; ++r) p[h][r] *= inv;
    }
    if (l15 == 0) {
#pragma unroll
      for (int h = 0; h < 4; ++h)
#pragma unroll
        for (int r = 0; r < 4; ++r) s_p[el * 32 + h * 8 + nbase + r] = p[h][r];
    }
  }
  __syncthreads();                                         // B3
  // stage WV
#pragma unroll
  for (int i = 0; i < 8; ++i)
    ((uint4*)s_stage)[tid + i * 256] = ((const uint4*)(wsb + WVW))[tid + i * 256];
  __syncthreads();                                         // B4

  // ---- V-GEMM fused with ctx accumulation -> s_ctx ----
#pragma unroll 1
  for (int mi = 0; mi < 2; ++mi) {
    int mt = wv * 2 + mi;
    int el = mt * 2 + (lg >> 1);
    bf16x8 a[4];
#pragma unroll
    for (int kk = 0; kk < 4; ++kk)
      a[kk] = *(const bf16x8*)(wsb + NBE + ((size_t)ebase * 8 + mt * 16 + l15) * 128 + kk * 32 + lg * 8);
    float4 p4[4];
#pragma unroll
    for (int h = 0; h < 4; ++h)
      p4[h] = *(const float4*)&s_p[el * 32 + h * 8 + (lg & 1) * 4];
    float cacc[8];
#pragma unroll
    for (int nt = 0; nt < 8; ++nt) {
      f32x4 v4 = {0.f, 0.f, 0.f, 0.f};
#pragma unroll
      for (int kk = 0; kk < 4; ++kk)
        v4 = mfma16(a[kk], frag128(s_stage, nt * 16 + l15, kk, lg), v4);
      int h = nt >> 1;
      cacc[nt] = p4[h].x * v4[0] + p4[h].y * v4[1] + p4[h].z * v4[2] + p4[h].w * v4[3];
    }
#pragma unroll
    for (int nt = 0; nt < 8; ++nt) cacc[nt] += __shfl_xor(cacc[nt], 16);
    if ((lg & 1) == 0) {
#pragma unroll
      for (int nt = 0; nt < 8; ++nt) {
        int c = nt * 16 + l15;
        s_ctx[el * 136 + c] = f2bf(cacc[nt] + wsp[8 * 128 + c]);
      }
    }
  }
  __syncthreads();                                         // B5  (s_stage dead from here)

  // ---- OUT proj -> s_f (f32, aliases stage[0,8448)) ----
  {
    bf16x8 a[4];
#pragma unroll
    for (int kk = 0; kk < 4; ++kk)
      a[kk] = *(const bf16x8*)(s_ctx + l15 * 136 + kk * 32 + lg * 8);
#pragma unroll
    for (int u = 0; u < 2; ++u) {
      int nt = wv * 2 + u;
      f32x4 acc = {0.f, 0.f, 0.f, 0.f};
#pragma unroll
      for (int kk = 0; kk < 4; ++kk) {
        bf16x8 b = *(const bf16x8*)(wsb + OWr + (nt * 16 + l15) * 128 + kk * 32 + lg * 8);
        acc = mfma16(a[kk], b, acc);
      }
      int c = nt * 16 + l15;
      float bo = wsp[9 * 128 + c];
#pragma unroll
      for (int r = 0; r < 4; ++r) s_f[(lg * 4 + r) * 132 + c] = acc[r] + bo;
    }
  }
  __syncthreads();                                         // B6

  // ---- LN(an) + agg select -> s_agg (aliases stage[8448,12800)) ----
  {
    int eo = wv * 4 + (l >> 4);
    float4 x0 = *(const float4*)&s_f[eo * 132 + l15 * 8];
    float4 x1 = *(const float4*)&s_f[eo * 132 + l15 * 8 + 4];
    float xa[8] = {x0.x, x0.y, x0.z, x0.w, x1.x, x1.y, x1.z, x1.w};
    float sm = 0.f, sq = 0.f;
#pragma unroll
    for (int j = 0; j < 8; ++j) { sm += xa[j]; sq = fmaf(xa[j], xa[j], sq); }
#pragma unroll
    for (int off = 1; off <= 8; off <<= 1) { sm += __shfl_xor(sm, off); sq += __shfl_xor(sq, off); }
    float mean = sm * 0.0078125f;
    float var = fmaf(sq, 0.0078125f, -mean * mean);
    float inv = rsqrtf(var + 1e-5f);
    int m = s_mask[eo];
    unsigned short o8[8];
    const unsigned short* cu = s_cur + eo * 136 + l15 * 8;
#pragma unroll
    for (int j = 0; j < 8; ++j) {
      int c = l15 * 8 + j;
      float v = (xa[j] - mean) * inv * wsp[10 * 128 + c] + wsp[11 * 128 + c];
      o8[j] = m ? f2bf(v) : cu[j];
    }
    uint4 u;
    u.x = (unsigned)o8[0] | ((unsigned)o8[1] << 16);
    u.y = (unsigned)o8[2] | ((unsigned)o8[3] << 16);
    u.z = (unsigned)o8[4] | ((unsigned)o8[5] << 16);
    u.w = (unsigned)o8[6] | ((unsigned)o8[7] << 16);
    *(uint4*)(s_agg + eo * 136 + l15 * 8) = u;
  }
  __syncthreads();                                         // B7

  // ---- P1 = [cur|agg] @ p1^T -> s_f ----
  {
    bf16x8 ac[4], ag[4];
#pragma unroll
    for (int kk = 0; kk < 4; ++kk) {
      ac[kk] = *(const bf16x8*)(s_cur + l15 * 136 + kk * 32 + lg * 8);
      ag[kk] = *(const bf16x8*)(s_agg + l15 * 136 + kk * 32 + lg * 8);
    }
#pragma unroll
    for (int u = 0; u < 2; ++u) {
      int nt = wv * 2 + u;
      f32x4 acc = {0.f, 0.f, 0.f, 0.f};
#pragma unroll
      for (int kk = 0; kk < 4; ++kk) {
        bf16x8 b = *(const bf16x8*)(wsb + P1Ar + (nt * 16 + l15) * 128 + kk * 32 + lg * 8);
        acc = mfma16(ac[kk], b, acc);
      }
#pragma unroll
      for (int kk = 0; kk < 4; ++kk) {
        bf16x8 b = *(const bf16x8*)(wsb + P1Br + (nt * 16 + l15) * 128 + kk * 32 + lg * 8);
        acc = mfma16(ag[kk], b, acc);
      }
      int c = nt * 16 + l15;
      float bb = wsp[12 * 128 + c];
#pragma unroll
      for (int r = 0; r < 4; ++r) s_f[(lg * 4 + r) * 132 + c] = acc[r] + bb;
    }
  }
  __syncthreads();                                         // B8

  // ---- LN(p1)+ReLU -> s_hh (aliases dead s_q) ----
  {
    int eo = wv * 4 + (l >> 4);
    float4 x0 = *(const float4*)&s_f[eo * 132 + l15 * 8];
    float4 x1 = *(const float4*)&s_f[eo * 132 + l15 * 8 + 4];
    float xa[8] = {x0.x, x0.y, x0.z, x0.w, x1.x, x1.y, x1.z, x1.w};
    float sm = 0.f, sq = 0.f;
#pragma unroll
    for (int j = 0; j < 8; ++j) { sm += xa[j]; sq = fmaf(xa[j], xa[j], sq); }
#pragma unroll
    for (int off = 1; off <= 8; off <<= 1) { sm += __shfl_xor(sm, off); sq += __shfl_xor(sq, off); }
    float mean = sm * 0.0078125f;
    float var = fmaf(sq, 0.0078125f, -mean * mean);
    float inv = rsqrtf(var + 1e-5f);
    unsigned short o8[8];
#pragma unroll
    for (int j = 0; j < 8; ++j) {
      int c = l15 * 8 + j;
      float v = (xa[j] - mean) * inv * wsp[13 * 128 + c] + wsp[14 * 128 + c];
      o8[j] = f2bf(fmaxf(v, 0.f));
    }
    uint4 u;
    u.x = (unsigned)o8[0] | ((unsigned)o8[1] << 16);
    u.y = (unsigned)o8[2] | ((unsigned)o8[3] << 16);
    u.z = (unsigned)o8[4] | ((unsigned)o8[5] << 16);
    u.w = (unsigned)o8[6] | ((unsigned)o8[7] << 16);
    *(uint4*)(s_hh + eo * 136 + l15 * 8) = u;
  }
  __syncthreads();                                         // B9

  // ---- P2 -> s_f ----
  {
    bf16x8 a[4];
#pragma unroll
    for (int kk = 0; kk < 4; ++kk)
      a[kk] = *(const bf16x8*)(s_hh + l15 * 136 + kk * 32 + lg * 8);
#pragma unroll
    for (int u = 0; u < 2; ++u) {
      int nt = wv * 2 + u;
      f32x4 acc = {0.f, 0.f, 0.f, 0.f};
#pragma unroll
      for (int kk = 0; kk < 4; ++kk) {
        bf16x8 b = *(const bf16x8*)(wsb + P2r + (nt * 16 + l15) * 128 + kk * 32 + lg * 8);
        acc = mfma16(a[kk], b, acc);
      }
      int c = nt * 16 + l15;
      float bb = wsp[15 * 128 + c];
#pragma unroll
      for (int r = 0; r < 4; ++r) s_f[(lg * 4 + r) * 132 + c] = acc[r] + bb;
    }
  }
  __syncthreads();                                         // B10

  // ---- final LN -> out ----
  {
    int eo = wv * 4 + (l >> 4);
    float4 x0 = *(const float4*)&s_f[eo * 132 + l15 * 8];
    float4 x1 = *(const float4*)&s_f[eo * 132 + l15 * 8 + 4];
    float xa[8] = {x0.x, x0.y, x0.z, x0.w, x1.x, x1.y, x1.z, x1.w};
    float sm = 0.f, sq = 0.f;
#pragma unroll
    for (int j = 0; j < 8; ++j) { sm += xa[j]; sq = fmaf(xa[j], xa[j], sq); }
#pragma unroll
    for (int off = 1; off <= 8; off <<= 1) { sm += __shfl_xor(sm, off); sq += __shfl_xor(sq, off); }
    float mean = sm * 0.0078125f;
    float var = fmaf(sq, 0.0078125f, -mean * mean);
    float inv = rsqrtf(var + 1e-5f);
    float o[8];
#pragma unroll
    for (int j = 0; j < 8; ++j) {
      int c = l15 * 8 + j;
      o[j] = (xa[j] - mean) * inv * wsp[16 * 128 + c] + wsp[17 * 128 + c];
    }
    float* op = out + (size_t)(ebase + eo) * 128 + l15 * 8;
    *(float4*)op = make_float4(o[0], o[1], o[2], o[3]);
    *(float4*)(op + 4) = make_float4(o[4], o[5], o[6], o[7]);
  }
}

// ================= fallback monolith (round-2, proven) =================
__global__ __launch_bounds__(NTH, 1)
void gcn_mfma(const float* __restrict__ cur_x, const float* __restrict__ nb_x,
              const int* __restrict__ nb_mask,
              const unsigned short* __restrict__ wsb, const float* __restrict__ wsp,
              float* __restrict__ out) {
  __shared__ __align__(16) unsigned short s_stage[20480];
  __shared__ __align__(16) unsigned short s_X[144 * 32];
  __shared__ __align__(16) unsigned short s_H[144 * 128];
  __shared__ __align__(16) unsigned short s_Enb[128 * 128];
  __shared__ __align__(16) unsigned short s_Ecur[16 * 128];
  __shared__ __align__(16) float s_q[16 * 132];
  __shared__ __align__(16) float s_p[16 * 32];
  __shared__ __align__(16) unsigned short s_ctx[16 * 128];
  __shared__ __align__(16) unsigned short s_agg[16 * 128];
  __shared__ __align__(16) unsigned short s_hh[16 * 128];
  __shared__ float s_prm[NPRM];
  __shared__ int s_mask[16];

  const int tid = threadIdx.x;
  const int wv = tid >> 6, l = tid & 63, l15 = l & 15, lg = l >> 4;
  const int sub = l >> 5, l32 = l & 31;
  const int ebase = blockIdx.x * TBE;
  const int eo = wv * 2 + sub;

  auto stage = [&](int srcOff) {
    const uint4* s = (const uint4*)(wsb + srcOff);
    uint4* d = (uint4*)s_stage;
#pragma unroll
    for (int i = 0; i < 4; ++i) d[tid + i * NTH] = s[tid + i * NTH];
  };
  auto ln_epi = [&](float (&vals)[8][4], int bslot, int gslot, int beslot, bool relu) {
    float sm[4] = {0, 0, 0, 0}, sq[4] = {0, 0, 0, 0};
#pragma unroll
    for (int nt = 0; nt < 8; ++nt) {
      float b = s_prm[bslot * 128 + nt * 16 + l15];
#pragma unroll
      for (int r = 0; r < 4; ++r) {
        float v = vals[nt][r] + b; vals[nt][r] = v;
        sm[r] += v; sq[r] = fmaf(v, v, sq[r]);
      }
    }
#pragma unroll
    for (int off = 8; off >= 1; off >>= 1)
#pragma unroll
      for (int r = 0; r < 4; ++r) {
        sm[r] += __shfl_xor(sm[r], off);
        sq[r] += __shfl_xor(sq[r], off);
      }
    float mean[4], inv[4];
#pragma unroll
    for (int r = 0; r < 4; ++r) {
      mean[r] = sm[r] * 0.0078125f;
      float var = fmaf(sq[r], 0.0078125f, -mean[r] * mean[r]);
      inv[r] = rsqrtf(var + 1e-5f);
    }
#pragma unroll
    for (int nt = 0; nt < 8; ++nt) {
      int col = nt * 16 + l15;
      float g = s_prm[gslot * 128 + col], be = s_prm[beslot * 128 + col];
#pragma unroll
      for (int r = 0; r < 4; ++r) {
        float v = (vals[nt][r] - mean[r]) * inv[r] * g + be;
        vals[nt][r] = relu ? fmaxf(v, 0.f) : v;
      }
    }
  };

  {
    const uint4* s = (const uint4*)(wsb + W1P);
    ((uint4*)(s_stage + 16384))[tid] = s[tid];
  }
  for (int i = tid; i < NPRM; i += NTH) s_prm[i] = wsp[i];
  for (int i = tid; i < 4608; i += NTH) {
    int row = i >> 5, col = i & 31;
    int e = (row * 57) >> 9, kind = row - e * 9;
    float v = 0.f;
    if (col < 16) {
      int ge = ebase + e;
      v = (kind == 0) ? cur_x[(size_t)ge * 16 + col]
                      : nb_x[((size_t)ge * 8 + (kind - 1)) * 16 + col];
    }
    s_X[row * 32 + ((((col >> 3) ^ (row & 3)) << 3) | (col & 7))] = f2bf(v);
  }
  if (tid < 16) {
    int m = 0; const int* mp = nb_mask + (size_t)(ebase + tid) * 8;
#pragma unroll
    for (int n = 0; n < 8; ++n) m |= (mp[n] > 0) << n;
    s_mask[tid] = m;
  }
  __syncthreads();

  stage(W2);
  for (int mt = wv; mt < 9; mt += 8) {
    bf16x8 a = frag32(s_X, mt * 16 + l15, lg);
    float vals[8][4];
#pragma unroll
    for (int nt = 0; nt < 8; ++nt) {
      f32x4 acc = {0.f, 0.f, 0.f, 0.f};
      acc = mfma16(a, frag32(s_stage + 16384, nt * 16 + l15, lg), acc);
#pragma unroll
      for (int r = 0; r < 4; ++r) vals[nt][r] = acc[r];
    }
    ln_epi(vals, 0, 1, 2, true);
#pragma unroll
    for (int nt = 0; nt < 8; ++nt)
#pragma unroll
      for (int r = 0; r < 4; ++r)
        st_bf16(s_H, mt * 16 + lg * 4 + r, nt * 16 + l15, vals[nt][r]);
  }
  __syncthreads();

  for (int mt = wv; mt < 9; mt += 8) {
    bf16x8 a[4];
#pragma unroll
    for (int kk = 0; kk < 4; ++kk) a[kk] = frag128(s_H, mt * 16 + l15, kk, lg);
    float vals[8][4];
#pragma unroll
    for (int nt = 0; nt < 8; ++nt) {
      f32x4 acc = {0.f, 0.f, 0.f, 0.f};
#pragma unroll
      for (int kk = 0; kk < 4; ++kk)
        acc = mfma16(a[kk], frag128(s_stage, nt * 16 + l15, kk, lg), acc);
#pragma unroll
      for (int r = 0; r < 4; ++r) vals[nt][r] = acc[r];
    }
    ln_epi(vals, 3, 4, 5, false);
#pragma unroll
    for (int nt = 0; nt < 8; ++nt) {
      int col = nt * 16 + l15;
#pragma unroll
      for (int r = 0; r < 4; ++r) {
        int R = mt * 16 + lg * 4 + r;
        int e = (R * 57) >> 9, kind = R - e * 9;
        if (kind == 0) st_bf16(s_Ecur, e, col, vals[nt][r]);
        else           st_bf16(s_Enb, e * 8 + kind - 1, col, vals[nt][r]);
      }
    }
  }
  __syncthreads();
  stage(WQ);
  __syncthreads();

  {
    f32x4 acc = {0.f, 0.f, 0.f, 0.f};
#pragma unroll
    for (int kk = 0; kk < 4; ++kk)
      acc = mfma16(frag128(s_Ecur, l15, kk, lg), frag128(s_stage, wv * 16 + l15, kk, lg), acc);
    int col = wv * 16 + l15; float bq = s_prm[6 * 128 + col];
#pragma unroll
    for (int r = 0; r < 4; ++r) s_q[(lg * 4 + r) * 132 + col] = acc[r] + bq;
  }
  __syncthreads();
  stage(WK);
  __syncthreads();

  {
    bf16x8 b[4];
#pragma unroll
    for (int kk = 0; kk < 4; ++kk) b[kk] = frag128(s_stage, wv * 16 + l15, kk, lg);
    int col = wv * 16 + l15; float bk = s_prm[7 * 128 + col];
#pragma unroll
    for (int mt = 0; mt < 8; ++mt) {
      f32x4 acc = {0.f, 0.f, 0.f, 0.f};
#pragma unroll
      for (int kk = 0; kk < 4; ++kk)
        acc = mfma16(frag128(s_Enb, mt * 16 + l15, kk, lg), b[kk], acc);
#pragma unroll
      for (int r = 0; r < 4; ++r)
        st_bf16(s_H, mt * 16 + lg * 4 + r, col, acc[r] + bk);
    }
  }
  __syncthreads();

  stage(WVW);
  {
    int h = l32 >> 3, n = l32 & 7;
    int krow = eo * 8 + n;
    float dot = 0.f;
#pragma unroll
    for (int j = 0; j < 4; ++j) {
      bf16x8 kf = *(const bf16x8*)(s_H + krow * 128 + (((h * 4 + j) ^ (krow & 7)) << 3));
      const float* qp = s_q + eo * 132 + h * 32 + j * 8;
      float4 q0 = *(const float4*)qp, q1 = *(const float4*)(qp + 4);
      dot = fmaf(__uint_as_float(((unsigned)(unsigned short)kf[0]) << 16), q0.x, dot);
      dot = fmaf(__uint_as_float(((unsigned)(unsigned short)kf[1]) << 16), q0.y, dot);
      dot = fmaf(__uint_as_float(((unsigned)(unsigned short)kf[2]) << 16), q0.z, dot);
      dot = fmaf(__uint_as_float(((unsigned)(unsigned short)kf[3]) << 16), q0.w, dot);
      dot = fmaf(__uint_as_float(((unsigned)(unsigned short)kf[4]) << 16), q1.x, dot);
      dot = fmaf(__uint_as_float(((unsigned)(unsigned short)kf[5]) << 16), q1.y, dot);
      dot = fmaf(__uint_as_float(((unsigned)(unsigned short)kf[6]) << 16), q1.z, dot);
      dot = fmaf(__uint_as_float(((unsigned)(unsigned short)kf[7]) << 16), q1.w, dot);
    }
    float sc = dot * 0.17677669529663687f;
    int m = s_mask[eo];
    bool use = (m == 0) || ((m >> n) & 1);
    float scm = use ? sc : -1e30f;
    float mx = scm;
#pragma unroll
    for (int off = 4; off >= 1; off >>= 1) mx = fmaxf(mx, __shfl_xor(mx, off));
    float p = use ? __expf(sc - mx) : 0.f;
    float sum = p;
#pragma unroll
    for (int off = 4; off >= 1; off >>= 1) sum += __shfl_xor(sum, off);
    s_p[eo * 32 + h * 8 + n] = p / sum;
  }
  __syncthreads();

  {
    bf16x8 b[4];
#pragma unroll
    for (int kk = 0; kk < 4; ++kk) b[kk] = frag128(s_stage, wv * 16 + l15, kk, lg);
    int col = wv * 16 + l15; float bv = s_prm[8 * 128 + col];
#pragma unroll
    for (int mt = 0; mt < 8; ++mt) {
      f32x4 acc = {0.f, 0.f, 0.f, 0.f};
#pragma unroll
      for (int kk = 0; kk < 4; ++kk)
        acc = mfma16(frag128(s_Enb, mt * 16 + l15, kk, lg), b[kk], acc);
#pragma unroll
      for (int r = 0; r < 4; ++r)
        st_bf16(s_H, mt * 16 + lg * 4 + r, col, acc[r] + bv);
    }
  }
  __syncthreads();

  stage(OW);
  {
#pragma unroll
    for (int cc = 0; cc < 4; ++cc) {
      int col = l32 + 32 * cc;
      float c = 0.f;
#pragma unroll
      for (int n = 0; n < 8; ++n)
        c = fmaf(s_p[eo * 32 + cc * 8 + n], ld_bf16(s_H, eo * 8 + n, col), c);
      st_bf16(s_ctx, eo, col, c);
    }
  }
  __syncthreads();

  {
    f32x4 acc = {0.f, 0.f, 0.f, 0.f};
#pragma unroll
    for (int kk = 0; kk < 4; ++kk)
      acc = mfma16(frag128(s_ctx, l15, kk, lg), frag128(s_stage, wv * 16 + l15, kk, lg), acc);
    int col = wv * 16 + l15; float bo = s_prm[9 * 128 + col];
#pragma unroll
    for (int r = 0; r < 4; ++r) s_q[(lg * 4 + r) * 132 + col] = acc[r] + bo;
  }
  __syncthreads();

  stage(P1A);
  {
    float4 x = *(const float4*)&s_q[eo * 132 + l32 * 4];
    float s = x.x + x.y + x.z + x.w;
    float qq = fmaf(x.x, x.x, fmaf(x.y, x.y, fmaf(x.z, x.z, x.w * x.w)));
#pragma unroll
    for (int off = 16; off >= 1; off >>= 1) { s += __shfl_xor(s, off); qq += __shfl_xor(qq, off); }
    float mean = s * 0.0078125f;
    float var = fmaf(qq, 0.0078125f, -mean * mean);
    float inv = rsqrtf(var + 1e-5f);
    int m = s_mask[eo];
    float xa[4] = {x.x, x.y, x.z, x.w}, r4[4];
#pragma unroll
    for (int c = 0; c < 4; ++c) {
      int col = l32 * 4 + c;
      float v = (xa[c] - mean) * inv * s_prm[10 * 128 + col] + s_prm[11 * 128 + col];
      r4[c] = m ? v : ld_bf16(s_Ecur, eo, col);
    }
    uint2 uu;
    uu.x = (unsigned)f2bf(r4[0]) | ((unsigned)f2bf(r4[1]) << 16);
    uu.y = (unsigned)f2bf(r4[2]) | ((unsigned)f2bf(r4[3]) << 16);
    *(uint2*)(s_agg + eo * 128 + (((l32 >> 1) ^ (eo & 7)) << 3) + (l32 & 1) * 4) = uu;
  }
  __syncthreads();

  f32x4 accP = {0.f, 0.f, 0.f, 0.f};
#pragma unroll
  for (int kk = 0; kk < 4; ++kk)
    accP = mfma16(frag128(s_Ecur, l15, kk, lg), frag128(s_stage, wv * 16 + l15, kk, lg), accP);
  __syncthreads();
  stage(P1B);
  __syncthreads();
  {
#pragma unroll
    for (int kk = 0; kk < 4; ++kk)
      accP = mfma16(frag128(s_agg, l15, kk, lg), frag128(s_stage, wv * 16 + l15, kk, lg), accP);
    int col = wv * 16 + l15; float b = s_prm[12 * 128 + col];
#pragma unroll
    for (int r = 0; r < 4; ++r) s_q[(lg * 4 + r) * 132 + col] = accP[r] + b;
  }
  __syncthreads();

  stage(P2W);
  {
    float4 x = *(const float4*)&s_q[eo * 132 + l32 * 4];
    float s = x.x + x.y + x.z + x.w;
    float qq = fmaf(x.x, x.x, fmaf(x.y, x.y, fmaf(x.z, x.z, x.w * x.w)));
#pragma unroll
    for (int off = 16; off >= 1; off >>= 1) { s += __shfl_xor(s, off); qq += __shfl_xor(qq, off); }
    float mean = s * 0.0078125f;
    float var = fmaf(qq, 0.0078125f, -mean * mean);
    float inv = rsqrtf(var + 1e-5f);
    float xa[4] = {x.x, x.y, x.z, x.w}, r4[4];
#pragma unroll
    for (int c = 0; c < 4; ++c) {
      int col = l32 * 4 + c;
      r4[c] = fmaxf((xa[c] - mean) * inv * s_prm[13 * 128 + col] + s_prm[14 * 128 + col], 0.f);
    }
    uint2 uu;
    uu.x = (unsigned)f2bf(r4[0]) | ((unsigned)f2bf(r4[1]) << 16);
    uu.y = (unsigned)f2bf(r4[2]) | ((unsigned)f2bf(r4[3]) << 16);
    *(uint2*)(s_hh + eo * 128 + (((l32 >> 1) ^ (eo & 7)) << 3) + (l32 & 1) * 4) = uu;
  }
  __syncthreads();

  {
    f32x4 acc = {0.f, 0.f, 0.f, 0.f};
#pragma unroll
    for (int kk = 0; kk < 4; ++kk)
      acc = mfma16(frag128(s_hh, l15, kk, lg), frag128(s_stage, wv * 16 + l15, kk, lg), acc);
    int col = wv * 16 + l15; float b = s_prm[15 * 128 + col];
#pragma unroll
    for (int r = 0; r < 4; ++r) s_q[(lg * 4 + r) * 132 + col] = acc[r] + b;
  }
  __syncthreads();

  {
    float4 x = *(const float4*)&s_q[eo * 132 + l32 * 4];
    float s = x.x + x.y + x.z + x.w;
    float qq = fmaf(x.x, x.x, fmaf(x.y, x.y, fmaf(x.z, x.z, x.w * x.w)));
#pragma unroll
    for (int off = 16; off >= 1; off >>= 1) { s += __shfl_xor(s, off); qq += __shfl_xor(qq, off); }
    float mean = s * 0.0078125f;
    float var = fmaf(qq, 0.0078125f, -mean * mean);
    float inv = rsqrtf(var + 1e-5f);
    float xa[4] = {x.x, x.y, x.z, x.w};
    float4 o;
    o.x = (xa[0] - mean) * inv * s_prm[16 * 128 + l32 * 4 + 0] + s_prm[17 * 128 + l32 * 4 + 0];
    o.y = (xa[1] - mean) * inv * s_prm[16 * 128 + l32 * 4 + 1] + s_prm[17 * 128 + l32 * 4 + 1];
    o.z = (xa[2] - mean) * inv * s_prm[16 * 128 + l32 * 4 + 2] + s_prm[17 * 128 + l32 * 4 + 2];
    o.w = (xa[3] - mean) * inv * s_prm[16 * 128 + l32 * 4 + 3] + s_prm[17 * 128 + l32 * 4 + 3];
    *(float4*)&out[(size_t)(ebase + eo) * 128 + l32 * 4] = o;
  }
}

extern "C" void kernel_launch(void* const* d_in, const int* in_sizes, int n_in,
                              void* d_out, int out_size, void* d_ws, size_t ws_size,
                              hipStream_t stream) {
  const float* cur_x   = (const float*)d_in[0];
  const float* nb_x    = (const float*)d_in[1];
  const int*   nbm     = (const int*)d_in[2];
  const float* enc_w1  = (const float*)d_in[3];
  const float* enc_b1  = (const float*)d_in[4];
  const float* enc_g1  = (const float*)d_in[5];
  const float* enc_be1 = (const float*)d_in[6];
  const float* enc_w2  = (const float*)d_in[7];
  const float* enc_b2  = (const float*)d_in[8];
  const float* enc_g2  = (const float*)d_in[9];
  const float* enc_be2 = (const float*)d_in[10];
  const float* in_pw   = (const float*)d_in[11];
  const float* in_pb   = (const float*)d_in[12];
  const float* out_w   = (const float*)d_in[13];
  const float* out_b   = (const float*)d_in[14];
  const float* an_g    = (const float*)d_in[15];
  const float* an_b    = (const float*)d_in[16];
  const float* p1_w    = (const float*)d_in[17];
  const float* p1_b    = (const float*)d_in[18];
  const float* p1_g    = (const float*)d_in[19];
  const float* p1_be   = (const float*)d_in[20];
  const float* p2_w    = (const float*)d_in[21];
  const float* p2_b    = (const float*)d_in[22];
  const float* p2_g    = (const float*)d_in[23];
  const float* p2_be   = (const float*)d_in[24];
  float* out = (float*)d_out;

  unsigned short* wsb = (unsigned short*)d_ws;
  float* wsp = (float*)(wsb + WS_BF16_TOT);
  const int B = in_sizes[0] / 16;
  const bool split = (ws_size >= SPLIT_NEED) && (B == 32768);

  prep<<<128, 256, 0, stream>>>(enc_w1, enc_w2, in_pw, out_w, p1_w, p2_w,
                                enc_b1, enc_g1, enc_be1, enc_b2, enc_g2, enc_be2,
                                in_pb, out_b, an_g, an_b, p1_b, p1_g, p1_be,
                                p2_b, p2_g, p2_be, wsb, wsp, split ? 1 : 0);

  if (split) {
    k1_enc<<<1152, 512, 0, stream>>>(cur_x, nb_x, wsb, wsp, wsb);
    k2_head<<<B / TBE, 256, 0, stream>>>(nbm, wsb, wsp, out);
  } else {
    gcn_mfma<<<B / TBE, NTH, 0, stream>>>(cur_x, nb_x, nbm, wsb, wsp, out);
  }
}